// Round 1
// baseline (1011.026 us; speedup 1.0000x reference)
//
#include <hip/hip_runtime.h>

// ---------------------------------------------------------------------------
// MaskedSelfAttention: B=4, T=2048, C=1024, H=16 heads, D=64, causal.
// Pipeline: cast x->bf16, transpose W->bf16, QKV proj (bf16 MFMA GEMM),
// flash attention (bf16 MFMA), output proj (bf16 MFMA, fp32 out).
// ---------------------------------------------------------------------------

typedef __attribute__((ext_vector_type(8))) short bhalf8;   // 8 x bf16
typedef __attribute__((ext_vector_type(4))) float f32x4;

#define BATCH 4
#define SEQ 2048
#define CDIM 1024
#define NHEAD 16
#define HDIM 64
#define MTOT (BATCH * SEQ)   // 8192

static __device__ inline unsigned short f2bf(float f) {
    unsigned int u = __float_as_uint(f);
    unsigned int r = (u + 0x7fffu + ((u >> 16) & 1u)) >> 16;
    return (unsigned short)r;
}

static __device__ inline f32x4 zero4() {
    f32x4 z = {0.f, 0.f, 0.f, 0.f};
    return z;
}

static __device__ inline f32x4 MFMA(bhalf8 a, bhalf8 b, f32x4 c) {
    return __builtin_amdgcn_mfma_f32_16x16x32_bf16(a, b, c, 0, 0, 0);
}

static __device__ inline void gload16(const void* g, void* l) {
    __builtin_amdgcn_global_load_lds(
        (const __attribute__((address_space(1))) unsigned int*)g,
        (__attribute__((address_space(3))) unsigned int*)l, 16, 0, 0);
}

// ---------------------------------------------------------------------------
// cast x (fp32 [M][K]) -> bf16 (short) [M][K], 8 elems/thread
// ---------------------------------------------------------------------------
__global__ __launch_bounds__(256) void cast_x_kernel(const float* __restrict__ x,
                                                     short* __restrict__ o, int n8) {
    int i = blockIdx.x * 256 + threadIdx.x;
    if (i >= n8) return;
    const float4* xv = (const float4*)x;
    float4 a = xv[i * 2];
    float4 b = xv[i * 2 + 1];
    bhalf8 r;
    r[0] = (short)f2bf(a.x); r[1] = (short)f2bf(a.y);
    r[2] = (short)f2bf(a.z); r[3] = (short)f2bf(a.w);
    r[4] = (short)f2bf(b.x); r[5] = (short)f2bf(b.y);
    r[6] = (short)f2bf(b.z); r[7] = (short)f2bf(b.w);
    *(bhalf8*)(o + (size_t)i * 8) = r;
}

// ---------------------------------------------------------------------------
// transpose+cast 4 weight matrices: W fp32 [K][N] -> Wt bf16 [N][K]
// grid (32,32,4), block (32,8)
// ---------------------------------------------------------------------------
__global__ __launch_bounds__(256) void wtrans_kernel(const float* __restrict__ W0,
                                                     const float* __restrict__ W1,
                                                     const float* __restrict__ W2,
                                                     const float* __restrict__ W3,
                                                     short* __restrict__ out) {
    __shared__ float t[32][33];
    const float* W = (blockIdx.z == 0) ? W0 : (blockIdx.z == 1) ? W1
                     : (blockIdx.z == 2) ? W2 : W3;
    short* o = out + (size_t)blockIdx.z * CDIM * CDIM;
    int n0 = blockIdx.x * 32, k0 = blockIdx.y * 32;
    int tx = threadIdx.x, ty = threadIdx.y;
    for (int j = 0; j < 4; ++j)
        t[ty + j * 8][tx] = W[(size_t)(k0 + ty + j * 8) * CDIM + n0 + tx];
    __syncthreads();
    for (int j = 0; j < 4; ++j)
        o[(size_t)(n0 + ty + j * 8) * CDIM + k0 + tx] = (short)f2bf(t[tx][ty + j * 8]);
}

// ---------------------------------------------------------------------------
// GEMM: C[m][n] = sum_k A[m][k] * Bt[n][k]  (+ bias), bf16 in, fp32 acc.
// Tile 128x128, BK=32, 256 threads (4 waves, 2x2), 16x16x32 MFMA.
// mode 1: fp32 out [M][Nn] += bias[n]         (final projection -> d_out)
// mode 2: bf16 out Q/K head-split [B][H][T][D], bias[n]
// mode 3: bf16 out V transposed  [B][H][D][T], bias[m] (swapped-operand GEMM)
// ---------------------------------------------------------------------------
__global__ __launch_bounds__(256) void gemm_bt(const short* __restrict__ A,
                                               const short* __restrict__ Bt,
                                               const float* __restrict__ bias,
                                               void* __restrict__ Out,
                                               int M, int Nn, int K, int mode) {
    __shared__ short Al[128 * 32];
    __shared__ short Bl[128 * 32];
    const int tid = threadIdx.x, lane = tid & 63, wid = tid >> 6;
    const int g = lane >> 4, t16 = lane & 15;
    const int tn = blockIdx.x * 128, tm = blockIdx.y * 128;
    const int wr = wid >> 1, wc = wid & 1;

    f32x4 acc[4][4];
    for (int i = 0; i < 4; ++i)
        for (int j = 0; j < 4; ++j) acc[i][j] = zero4();

    for (int k0 = 0; k0 < K; k0 += 32) {
        __syncthreads();
        for (int it = 0; it < 2; ++it) {
            int c = it * 256 + tid;          // chunk 0..511 (16B each)
            int row = c >> 2, kc = c & 3;    // 4 chunks per 32-elem row
            char* ldsbase = (char*)Al + it * 4096 + wid * 1024;
            gload16(A + (size_t)(tm + row) * K + k0 + kc * 8, ldsbase);
            char* ldsbase2 = (char*)Bl + it * 4096 + wid * 1024;
            gload16(Bt + (size_t)(tn + row) * K + k0 + kc * 8, ldsbase2);
        }
        __syncthreads();
        bhalf8 af[4], bfr[4];
        for (int mi = 0; mi < 4; ++mi)
            af[mi] = *(const bhalf8*)(Al + (wr * 64 + mi * 16 + t16) * 32 + g * 8);
        for (int ni = 0; ni < 4; ++ni)
            bfr[ni] = *(const bhalf8*)(Bl + (wc * 64 + ni * 16 + t16) * 32 + g * 8);
        for (int mi = 0; mi < 4; ++mi)
            for (int ni = 0; ni < 4; ++ni)
                acc[mi][ni] = MFMA(af[mi], bfr[ni], acc[mi][ni]);
    }

    // epilogue: C/D frag: row = g*4 + r, col = t16
    for (int mi = 0; mi < 4; ++mi) {
        for (int ni = 0; ni < 4; ++ni) {
            int mbase = tm + wr * 64 + mi * 16 + g * 4;
            int ncol = tn + wc * 64 + ni * 16 + t16;
            float bcol = (mode != 3) ? bias[ncol] : 0.f;
            for (int r = 0; r < 4; ++r) {
                int m = mbase + r;
                float v = acc[mi][ni][r];
                if (mode == 1) {
                    ((float*)Out)[(size_t)m * Nn + ncol] = v + bcol;
                } else if (mode == 2) {
                    int b = m >> 11, t = m & 2047, h = ncol >> 6, d = ncol & 63;
                    ((unsigned short*)Out)[(((size_t)((b * NHEAD + h) * SEQ + t)) << 6) + d] =
                        f2bf(v + bcol);
                } else {  // mode 3: rows are (h,d), cols are (b,t)
                    float brow = bias[m];
                    int h = m >> 6, d = m & 63, b = ncol >> 11, t = ncol & 2047;
                    ((unsigned short*)Out)[(((size_t)((b * NHEAD + h) * HDIM + d)) << 11) + t] =
                        f2bf(v + brow);
                }
            }
        }
    }
}

// ---------------------------------------------------------------------------
// Flash attention, causal. One workgroup (4 waves) per (b,h, 64-row q-tile).
// Q,K: bf16 [B*H][T][D]; V: bf16 [B*H][D][T]; ctx out: bf16 [M][C] merged heads.
// KV tile = 64. K/V staged via global_load_lds with XOR-swizzled source
// (linear LDS dest, swizzled read) to avoid 128B-stride bank conflicts.
// ---------------------------------------------------------------------------
__global__ __launch_bounds__(256) void attn_kernel(const short* __restrict__ Q,
                                                   const short* __restrict__ K,
                                                   const short* __restrict__ V,
                                                   unsigned short* __restrict__ ctx) {
    __shared__ short Kl[64 * 64];
    __shared__ short Vl[64 * 64];
    __shared__ short Pl[4][16 * 64];

    const int tid = threadIdx.x, lane = tid & 63, w = tid >> 6;
    const int g = lane >> 4, t16 = lane & 15;
    const int bh = blockIdx.x >> 5, qt = blockIdx.x & 31;
    const int qbase = qt * 64;

    const short* Qh = Q + ((size_t)bh << 17);   // 2048*64
    const short* Kh = K + ((size_t)bh << 17);
    const short* Vh = V + ((size_t)bh << 17);

    // Q fragments (A-operand), direct from global: row = qbase + w*16 + t16
    bhalf8 qf[2];
    {
        const short* qp = Qh + ((size_t)(qbase + w * 16 + t16) << 6) + g * 8;
        qf[0] = *(const bhalf8*)(qp);
        qf[1] = *(const bhalf8*)(qp + 32);
    }

    f32x4 acc[4];
    for (int i = 0; i < 4; ++i) acc[i] = zero4();
    float mrow[4], lrow[4];
    for (int r = 0; r < 4; ++r) { mrow[r] = -1e30f; lrow[r] = 0.f; }
    const float SC = 0.125f * 1.4426950408889634f;  // 1/sqrt(64) * log2(e)

    for (int kv = 0; kv <= qt; ++kv) {
        __syncthreads();   // all waves done reading previous K/V tile
        for (int it = 0; it < 2; ++it) {
            int c = it * 256 + tid;                 // chunk 0..511
            int s = c >> 3;                         // K tile row (s), 8 chunks/row
            int dc = (c & 7) ^ (s & 7);             // pre-swizzled source chunk
            gload16(Kh + ((size_t)(kv * 64 + s) << 6) + dc * 8,
                    (char*)Kl + it * 4096 + w * 1024);
            int d = c >> 3;                         // V tile row (d)
            int sc2 = (c & 7) ^ (d & 7);
            gload16(Vh + ((size_t)d << 11) + kv * 64 + sc2 * 8,
                    (char*)Vl + it * 4096 + w * 1024);
        }
        __syncthreads();   // staging complete (vmcnt drained at barrier)

        // ---- QK^T : logits 16x64 per wave ----
        f32x4 lg[4];
        for (int cb = 0; cb < 4; ++cb) {
            int s = cb * 16 + t16;
            int sw = (s & 7) << 4;
            const char* rowp = (const char*)Kl + s * 128;
            bhalf8 k0 = *(const bhalf8*)(rowp + ((g * 16) ^ sw));
            bhalf8 k1 = *(const bhalf8*)(rowp + ((64 + g * 16) ^ sw));
            f32x4 z = zero4();
            z = MFMA(qf[0], k0, z);
            z = MFMA(qf[1], k1, z);
            lg[cb] = z;
        }

        // ---- scale + causal mask (base-2 domain) ----
        float p[4][4];
        if (kv == qt) {
            for (int cb = 0; cb < 4; ++cb) {
                int col = kv * 64 + cb * 16 + t16;
                for (int r = 0; r < 4; ++r) {
                    int row = qbase + w * 16 + g * 4 + r;
                    float v = lg[cb][r] * SC;
                    p[cb][r] = (col > row) ? -1e30f : v;
                }
            }
        } else {
            for (int cb = 0; cb < 4; ++cb)
                for (int r = 0; r < 4; ++r) p[cb][r] = lg[cb][r] * SC;
        }

        // ---- online softmax ----
        float corr[4];
        for (int r = 0; r < 4; ++r) {
            float tmax = fmaxf(fmaxf(p[0][r], p[1][r]), fmaxf(p[2][r], p[3][r]));
            for (int off = 1; off < 16; off <<= 1)
                tmax = fmaxf(tmax, __shfl_xor(tmax, off, 64));
            float mnew = fmaxf(mrow[r], tmax);
            corr[r] = exp2f(mrow[r] - mnew);
            mrow[r] = mnew;
        }
        for (int r = 0; r < 4; ++r) {
            float s4 = 0.f;
            for (int cb = 0; cb < 4; ++cb) {
                p[cb][r] = exp2f(p[cb][r] - mrow[r]);
                s4 += p[cb][r];
            }
            for (int off = 1; off < 16; off <<= 1)
                s4 += __shfl_xor(s4, off, 64);
            lrow[r] = lrow[r] * corr[r] + s4;
        }
        for (int i = 0; i < 4; ++i)
            for (int r = 0; r < 4; ++r) acc[i][r] *= corr[r];

        // ---- P -> bf16, transpose via per-wave swizzled LDS ----
        for (int cb = 0; cb < 4; ++cb) {
            for (int r = 0; r < 4; ++r) {
                int lr = g * 4 + r;
                int byte = (lr * 128 + (cb * 16 + t16) * 2) ^ ((lr & 7) << 4);
                *(unsigned short*)((char*)Pl[w] + byte) = f2bf(p[cb][r]);
            }
        }

        // ---- PV: ctx += P @ V ----
        for (int kk = 0; kk < 2; ++kk) {
            int abyte = (t16 * 128 + kk * 64 + g * 16) ^ ((t16 & 7) << 4);
            bhalf8 pa = *(const bhalf8*)((const char*)Pl[w] + abyte);
            for (int db = 0; db < 4; ++db) {
                int drow = db * 16 + t16;
                int vbyte = drow * 128 + ((kk * 64 + g * 16) ^ ((drow & 7) << 4));
                bhalf8 vf = *(const bhalf8*)((const char*)Vl + vbyte);
                acc[db] = MFMA(pa, vf, acc[db]);
            }
        }
    }

    // ---- normalize + write ctx bf16 [M][C] (merged heads) ----
    int b = bh >> 4, h = bh & 15;
    for (int r = 0; r < 4; ++r) {
        float inv = 1.f / lrow[r];
        int t = qbase + w * 16 + g * 4 + r;
        size_t rowoff = (((size_t)(b * SEQ + t)) << 10) + h * 64;
        for (int db = 0; db < 4; ++db)
            ctx[rowoff + db * 16 + t16] = f2bf(acc[db][r] * inv);
    }
}

// ---------------------------------------------------------------------------
// launch
// ---------------------------------------------------------------------------
extern "C" void kernel_launch(void* const* d_in, const int* in_sizes, int n_in,
                              void* d_out, int out_size, void* d_ws, size_t ws_size,
                              hipStream_t stream) {
    const float* x  = (const float*)d_in[0];
    const float* Wq = (const float*)d_in[1];
    const float* bq = (const float*)d_in[2];
    const float* Wk = (const float*)d_in[3];
    const float* bk = (const float*)d_in[4];
    const float* Wv = (const float*)d_in[5];
    const float* bv = (const float*)d_in[6];
    const float* Wo = (const float*)d_in[7];
    const float* bo = (const float*)d_in[8];

    char* ws = (char*)d_ws;
    // workspace layout (88 MB total)
    short* x16 = (short*)(ws);                                // 16 MB
    short* Wt  = (short*)(ws + (size_t)16 * 1024 * 1024);     // 4 x 2 MB (q,k,v,o)
    short* Wqt = Wt;
    short* Wkt = Wt + (size_t)1 * CDIM * CDIM;
    short* Wvt = Wt + (size_t)2 * CDIM * CDIM;
    short* Wot = Wt + (size_t)3 * CDIM * CDIM;
    short* Qb  = (short*)(ws + (size_t)24 * 1024 * 1024);     // 16 MB [BH][T][D]
    short* Kb  = (short*)(ws + (size_t)40 * 1024 * 1024);     // 16 MB [BH][T][D]
    short* Vb  = (short*)(ws + (size_t)56 * 1024 * 1024);     // 16 MB [BH][D][T]
    short* Ctx = (short*)(ws + (size_t)72 * 1024 * 1024);     // 16 MB [M][C]

    cast_x_kernel<<<dim3(MTOT * CDIM / 8 / 256), dim3(256), 0, stream>>>(x, x16,
                                                                         MTOT * CDIM / 8);
    wtrans_kernel<<<dim3(32, 32, 4), dim3(32, 8), 0, stream>>>(Wq, Wk, Wv, Wo, Wt);

    // Q, K projections: C[m][n] = x @ W + b, head-split output
    gemm_bt<<<dim3(CDIM / 128, MTOT / 128), dim3(256), 0, stream>>>(
        x16, Wqt, bq, Qb, MTOT, CDIM, CDIM, 2);
    gemm_bt<<<dim3(CDIM / 128, MTOT / 128), dim3(256), 0, stream>>>(
        x16, Wkt, bk, Kb, MTOT, CDIM, CDIM, 2);
    // V projection, swapped operands: C'[n][m] = (Wv^T x^T), V^T layout out
    gemm_bt<<<dim3(MTOT / 128, CDIM / 128), dim3(256), 0, stream>>>(
        Wvt, x16, bv, Vb, CDIM, MTOT, CDIM, 3);

    // attention
    attn_kernel<<<dim3(BATCH * NHEAD * (SEQ / 64)), dim3(256), 0, stream>>>(
        Qb, Kb, Vb, (unsigned short*)Ctx);

    // output projection -> fp32 d_out
    gemm_bt<<<dim3(CDIM / 128, MTOT / 128), dim3(256), 0, stream>>>(
        Ctx, Wot, bo, d_out, MTOT, CDIM, CDIM, 1);
}

// Round 2
// 923.783 us; speedup vs baseline: 1.0944x; 1.0944x over previous
//
#include <hip/hip_runtime.h>

// ---------------------------------------------------------------------------
// MaskedSelfAttention: B=4, T=2048, C=1024, H=16 heads, D=64, causal.
// cast x->bf16, transpose W->bf16, fused QK proj + V proj (bf16 MFMA GEMM),
// double-buffered flash attention (bf16 MFMA), output proj (fp32 out).
// ---------------------------------------------------------------------------

typedef __attribute__((ext_vector_type(8))) short bhalf8;   // 8 x bf16
typedef __attribute__((ext_vector_type(4))) float f32x4;

#define BATCH 4
#define SEQ 2048
#define CDIM 1024
#define NHEAD 16
#define HDIM 64
#define MTOT (BATCH * SEQ)   // 8192

static __device__ inline unsigned short f2bf(float f) {
    unsigned int u = __float_as_uint(f);
    unsigned int r = (u + 0x7fffu + ((u >> 16) & 1u)) >> 16;
    return (unsigned short)r;
}

static __device__ inline f32x4 zero4() {
    f32x4 z = {0.f, 0.f, 0.f, 0.f};
    return z;
}

static __device__ inline f32x4 MFMA(bhalf8 a, bhalf8 b, f32x4 c) {
    return __builtin_amdgcn_mfma_f32_16x16x32_bf16(a, b, c, 0, 0, 0);
}

static __device__ inline void gload16(const void* g, void* l) {
    __builtin_amdgcn_global_load_lds(
        (const __attribute__((address_space(1))) unsigned int*)g,
        (__attribute__((address_space(3))) unsigned int*)l, 16, 0, 0);
}

// ---------------------------------------------------------------------------
// cast x (fp32 [M][K]) -> bf16 (short) [M][K], 8 elems/thread
// ---------------------------------------------------------------------------
__global__ __launch_bounds__(256) void cast_x_kernel(const float* __restrict__ x,
                                                     short* __restrict__ o, int n8) {
    int i = blockIdx.x * 256 + threadIdx.x;
    if (i >= n8) return;
    const float4* xv = (const float4*)x;
    float4 a = xv[i * 2];
    float4 b = xv[i * 2 + 1];
    bhalf8 r;
    r[0] = (short)f2bf(a.x); r[1] = (short)f2bf(a.y);
    r[2] = (short)f2bf(a.z); r[3] = (short)f2bf(a.w);
    r[4] = (short)f2bf(b.x); r[5] = (short)f2bf(b.y);
    r[6] = (short)f2bf(b.z); r[7] = (short)f2bf(b.w);
    *(bhalf8*)(o + (size_t)i * 8) = r;
}

// ---------------------------------------------------------------------------
// transpose+cast 4 weight matrices: W fp32 [K][N] -> Wt bf16 [N][K]
// ---------------------------------------------------------------------------
__global__ __launch_bounds__(256) void wtrans_kernel(const float* __restrict__ W0,
                                                     const float* __restrict__ W1,
                                                     const float* __restrict__ W2,
                                                     const float* __restrict__ W3,
                                                     short* __restrict__ out) {
    __shared__ float t[32][33];
    const float* W = (blockIdx.z == 0) ? W0 : (blockIdx.z == 1) ? W1
                     : (blockIdx.z == 2) ? W2 : W3;
    short* o = out + (size_t)blockIdx.z * CDIM * CDIM;
    int n0 = blockIdx.x * 32, k0 = blockIdx.y * 32;
    int tx = threadIdx.x, ty = threadIdx.y;
    for (int j = 0; j < 4; ++j)
        t[ty + j * 8][tx] = W[(size_t)(k0 + ty + j * 8) * CDIM + n0 + tx];
    __syncthreads();
    for (int j = 0; j < 4; ++j)
        o[(size_t)(n0 + ty + j * 8) * CDIM + k0 + tx] = (short)f2bf(t[tx][ty + j * 8]);
}

// ---------------------------------------------------------------------------
// GEMM: C[m][n] = sum_k A[m][k] * Bt[n][k]  (+ bias), bf16 in, fp32 acc.
// Tile 128x128, BK=32, 256 threads (4 waves, 2x2), 16x16x32 MFMA.
// mode 1: fp32 out [M][Nn] + bias[n]          (final projection -> d_out)
// mode 3: bf16 out V transposed [B][H][D][T], bias[m] (swapped-operand GEMM)
// mode 5: fused Q/K: Nn=2048; part=hh>>4 (0->Q,1->K), bf16 [B][H][T][D]
// ---------------------------------------------------------------------------
__global__ __launch_bounds__(256) void gemm_bt(const short* __restrict__ A,
                                               const short* __restrict__ Bt,
                                               const float* __restrict__ bias,
                                               const float* __restrict__ bias2,
                                               void* __restrict__ Out,
                                               int M, int Nn, int K, int mode) {
    __shared__ short Al[128 * 32];
    __shared__ short Bl[128 * 32];
    const int tid = threadIdx.x, lane = tid & 63, wid = tid >> 6;
    const int g = lane >> 4, t16 = lane & 15;
    const int tn = blockIdx.x * 128, tm = blockIdx.y * 128;
    const int wr = wid >> 1, wc = wid & 1;

    f32x4 acc[4][4];
    for (int i = 0; i < 4; ++i)
        for (int j = 0; j < 4; ++j) acc[i][j] = zero4();

    for (int k0 = 0; k0 < K; k0 += 32) {
        __syncthreads();
        for (int it = 0; it < 2; ++it) {
            int c = it * 256 + tid;          // chunk 0..511 (16B each)
            int row = c >> 2, kc = c & 3;    // 4 chunks per 32-elem row
            char* ldsbase = (char*)Al + it * 4096 + wid * 1024;
            gload16(A + (size_t)(tm + row) * K + k0 + kc * 8, ldsbase);
            char* ldsbase2 = (char*)Bl + it * 4096 + wid * 1024;
            gload16(Bt + (size_t)(tn + row) * K + k0 + kc * 8, ldsbase2);
        }
        __syncthreads();
        bhalf8 af[4], bfr[4];
        for (int mi = 0; mi < 4; ++mi)
            af[mi] = *(const bhalf8*)(Al + (wr * 64 + mi * 16 + t16) * 32 + g * 8);
        for (int ni = 0; ni < 4; ++ni)
            bfr[ni] = *(const bhalf8*)(Bl + (wc * 64 + ni * 16 + t16) * 32 + g * 8);
        for (int mi = 0; mi < 4; ++mi)
            for (int ni = 0; ni < 4; ++ni)
                acc[mi][ni] = MFMA(af[mi], bfr[ni], acc[mi][ni]);
    }

    // epilogue: C/D frag: row = g*4 + r, col = t16
    for (int mi = 0; mi < 4; ++mi) {
        for (int ni = 0; ni < 4; ++ni) {
            int mbase = tm + wr * 64 + mi * 16 + g * 4;
            int ncol = tn + wc * 64 + ni * 16 + t16;
            float bcol = 0.f;
            if (mode == 1) bcol = bias[ncol];
            else if (mode == 5) bcol = (ncol < CDIM) ? bias[ncol] : bias2[ncol - CDIM];
            for (int r = 0; r < 4; ++r) {
                int m = mbase + r;
                float v = acc[mi][ni][r];
                if (mode == 1) {
                    ((float*)Out)[(size_t)m * Nn + ncol] = v + bcol;
                } else if (mode == 5) {
                    int b = m >> 11, t = m & 2047, hh = ncol >> 6, d = ncol & 63;
                    int part = hh >> 4, h = hh & 15;
                    ((unsigned short*)Out)[(((size_t)((part * 64 + b * NHEAD + h) * SEQ + t)) << 6) + d] =
                        f2bf(v + bcol);
                } else {  // mode 3: rows are (h,d), cols are (b,t)
                    float brow = bias[m];
                    int h = m >> 6, d = m & 63, b = ncol >> 11, t = ncol & 2047;
                    ((unsigned short*)Out)[(((size_t)((b * NHEAD + h) * HDIM + d)) << 11) + t] =
                        f2bf(v + brow);
                }
            }
        }
    }
}

// ---------------------------------------------------------------------------
// Flash attention, causal, double-buffered. 4 waves per block; each wave owns
// 32 q-rows (QBLK=128 per block). KV tile = 64. Q,K: bf16 [B*H][T][D];
// V: bf16 [B*H][D][T]; ctx out: bf16 [M][C] merged heads.
// T3-minimum pipeline: stage tile t+1 -> compute tile t -> syncthreads
// (the barrier's built-in vmcnt(0) drain is the staging wait).
// ---------------------------------------------------------------------------
__global__ __launch_bounds__(256) void attn_kernel(const short* __restrict__ Q,
                                                   const short* __restrict__ K,
                                                   const short* __restrict__ V,
                                                   unsigned short* __restrict__ ctx) {
    __shared__ short Kl[2][64 * 64];
    __shared__ short Vl[2][64 * 64];
    __shared__ short Pl[4][32 * 64];

    const int tid = threadIdx.x, lane = tid & 63, w = tid >> 6;
    const int g = lane >> 4, t16 = lane & 15;

    // chunked XCD swizzle (1024 blocks, 128/XCD = 8 full heads) + heavy-first
    int orig = blockIdx.x;
    int swz = (orig & 7) * 128 + (orig >> 3);
    const int bh = swz >> 4;
    const int qti = 15 - (swz & 15);
    const int qbase = qti * 128;
    const int nt = 2 * qti + 2;

    const short* Qh = Q + ((size_t)bh << 17);   // 2048*64
    const short* Kh = K + ((size_t)bh << 17);
    const short* Vh = V + ((size_t)bh << 17);   // [D][T]

    // Q fragments: A-operand row = t16, k = g*8+j. 2 row-frags x 2 k-frags.
    bhalf8 qf[2][2];
    for (int rf = 0; rf < 2; ++rf) {
        const short* qp = Qh + ((size_t)(qbase + w * 32 + rf * 16 + t16) << 6) + g * 8;
        qf[rf][0] = *(const bhalf8*)(qp);
        qf[rf][1] = *(const bhalf8*)(qp + 32);
    }

    f32x4 acc[2][4];
    for (int rf = 0; rf < 2; ++rf)
        for (int i = 0; i < 4; ++i) acc[rf][i] = zero4();
    float mrow[2][4], lrow[2][4];
    for (int rf = 0; rf < 2; ++rf)
        for (int r = 0; r < 4; ++r) { mrow[rf][r] = -1e30f; lrow[rf][r] = 0.f; }
    const float SC = 0.125f * 1.4426950408889634f;  // 1/sqrt(64) * log2(e)

#define STAGE(kv_, bb_)                                                          \
    do {                                                                         \
        for (int it = 0; it < 2; ++it) {                                         \
            int c = it * 256 + tid;                                              \
            int s = c >> 3;                                                      \
            int dc = (c & 7) ^ (s & 7);                                          \
            gload16(Kh + ((size_t)((kv_) * 64 + s) << 6) + dc * 8,               \
                    (char*)Kl[bb_] + it * 4096 + w * 1024);                      \
            int sc2 = (c & 7) ^ (s & 7);                                         \
            gload16(Vh + ((size_t)s << 11) + (kv_) * 64 + sc2 * 8,               \
                    (char*)Vl[bb_] + it * 4096 + w * 1024);                      \
        }                                                                        \
    } while (0)

    STAGE(0, 0);
    __syncthreads();

    int buf = 0;
    for (int kv = 0; kv < nt; ++kv) {
        if (kv + 1 < nt) STAGE(kv + 1, buf ^ 1);

        // ---- QK^T ----
        f32x4 lg[2][4];
#pragma unroll
        for (int cb = 0; cb < 4; ++cb) {
            int s = cb * 16 + t16;
            int sw = (s & 7) << 4;
            const char* rowp = (const char*)Kl[buf] + s * 128;
            bhalf8 k0 = *(const bhalf8*)(rowp + ((g * 16) ^ sw));
            bhalf8 k1 = *(const bhalf8*)(rowp + ((64 + g * 16) ^ sw));
#pragma unroll
            for (int rf = 0; rf < 2; ++rf) {
                f32x4 z = zero4();
                z = MFMA(qf[rf][0], k0, z);
                z = MFMA(qf[rf][1], k1, z);
                lg[rf][cb] = z;
            }
        }

        // ---- scale + causal mask (base-2 domain) ----
        float p[2][4][4];
        bool domask = (kv >= 2 * qti);
#pragma unroll
        for (int rf = 0; rf < 2; ++rf)
#pragma unroll
            for (int cb = 0; cb < 4; ++cb) {
                int col = kv * 64 + cb * 16 + t16;
#pragma unroll
                for (int r = 0; r < 4; ++r) {
                    int row = qbase + w * 32 + rf * 16 + g * 4 + r;
                    float v = lg[rf][cb][r] * SC;
                    p[rf][cb][r] = (domask && col > row) ? -1e30f : v;
                }
            }

        // ---- online softmax ----
#pragma unroll
        for (int rf = 0; rf < 2; ++rf) {
            float corr[4];
#pragma unroll
            for (int r = 0; r < 4; ++r) {
                float tmax = fmaxf(fmaxf(p[rf][0][r], p[rf][1][r]),
                                   fmaxf(p[rf][2][r], p[rf][3][r]));
                for (int off = 1; off < 16; off <<= 1)
                    tmax = fmaxf(tmax, __shfl_xor(tmax, off, 64));
                float mnew = fmaxf(mrow[rf][r], tmax);
                corr[r] = exp2f(mrow[rf][r] - mnew);
                mrow[rf][r] = mnew;
            }
#pragma unroll
            for (int r = 0; r < 4; ++r) {
                float s4 = 0.f;
#pragma unroll
                for (int cb = 0; cb < 4; ++cb) {
                    p[rf][cb][r] = exp2f(p[rf][cb][r] - mrow[rf][r]);
                    s4 += p[rf][cb][r];
                }
                for (int off = 1; off < 16; off <<= 1)
                    s4 += __shfl_xor(s4, off, 64);
                lrow[rf][r] = lrow[rf][r] * corr[r] + s4;
            }
#pragma unroll
            for (int i = 0; i < 4; ++i)
#pragma unroll
                for (int r = 0; r < 4; ++r) acc[rf][i][r] *= corr[r];
        }

        // ---- P -> bf16 transpose via per-wave swizzled LDS ----
#pragma unroll
        for (int rf = 0; rf < 2; ++rf)
#pragma unroll
            for (int cb = 0; cb < 4; ++cb)
#pragma unroll
                for (int r = 0; r < 4; ++r) {
                    int lr = rf * 16 + g * 4 + r;
                    int byte = (lr * 128 + (cb * 16 + t16) * 2) ^ ((lr & 7) << 4);
                    *(unsigned short*)((char*)Pl[w] + byte) = f2bf(p[rf][cb][r]);
                }

        // ---- PV: ctx += P @ V ----
#pragma unroll
        for (int kk = 0; kk < 2; ++kk) {
            bhalf8 vf[4];
#pragma unroll
            for (int db = 0; db < 4; ++db) {
                int d = db * 16 + t16;
                int vbyte = d * 128 + ((kk * 64 + g * 16) ^ ((d & 7) << 4));
                vf[db] = *(const bhalf8*)((const char*)Vl[buf] + vbyte);
            }
#pragma unroll
            for (int rf = 0; rf < 2; ++rf) {
                int lr2 = rf * 16 + t16;
                int abyte = (lr2 * 128 + kk * 64 + g * 16) ^ ((lr2 & 7) << 4);
                bhalf8 pa = *(const bhalf8*)((const char*)Pl[w] + abyte);
#pragma unroll
                for (int db = 0; db < 4; ++db)
                    acc[rf][db] = MFMA(pa, vf[db], acc[rf][db]);
            }
        }

        __syncthreads();   // drains vmcnt(0): staged tile ready; LDS reads done
        buf ^= 1;
    }
#undef STAGE

    // ---- normalize + write ctx bf16 [M][C] (merged heads) ----
    int b = bh >> 4, h = bh & 15;
#pragma unroll
    for (int rf = 0; rf < 2; ++rf)
#pragma unroll
        for (int r = 0; r < 4; ++r) {
            float inv = 1.f / lrow[rf][r];
            int t = qbase + w * 32 + rf * 16 + g * 4 + r;
            size_t rowoff = (((size_t)(b * SEQ + t)) << 10) + h * 64;
#pragma unroll
            for (int db = 0; db < 4; ++db)
                ctx[rowoff + db * 16 + t16] = f2bf(acc[rf][db][r] * inv);
        }
}

// ---------------------------------------------------------------------------
// launch
// ---------------------------------------------------------------------------
extern "C" void kernel_launch(void* const* d_in, const int* in_sizes, int n_in,
                              void* d_out, int out_size, void* d_ws, size_t ws_size,
                              hipStream_t stream) {
    const float* x  = (const float*)d_in[0];
    const float* Wq = (const float*)d_in[1];
    const float* bq = (const float*)d_in[2];
    const float* Wk = (const float*)d_in[3];
    const float* bk = (const float*)d_in[4];
    const float* Wv = (const float*)d_in[5];
    const float* bv = (const float*)d_in[6];
    const float* Wo = (const float*)d_in[7];
    const float* bo = (const float*)d_in[8];

    char* ws = (char*)d_ws;
    short* x16 = (short*)(ws);                                // 16 MB
    short* Wt  = (short*)(ws + (size_t)16 * 1024 * 1024);     // 4 x 2 MB (q,k,v,o)
    short* Wqt = Wt;                                          // Wq,Wk contiguous!
    short* Wvt = Wt + (size_t)2 * CDIM * CDIM;
    short* Wot = Wt + (size_t)3 * CDIM * CDIM;
    short* Qb  = (short*)(ws + (size_t)24 * 1024 * 1024);     // 16 MB [BH][T][D]
    short* Vb  = (short*)(ws + (size_t)56 * 1024 * 1024);     // 16 MB [BH][D][T]
    short* Ctx = (short*)(ws + (size_t)72 * 1024 * 1024);     // 16 MB [M][C]

    cast_x_kernel<<<dim3(MTOT * CDIM / 8 / 256), dim3(256), 0, stream>>>(
        x, x16, MTOT * CDIM / 8);
    wtrans_kernel<<<dim3(32, 32, 4), dim3(32, 8), 0, stream>>>(Wq, Wk, Wv, Wo, Wt);

    // fused Q+K projection: Nn = 2048 (Wqt||Wkt), head-split output to Qb||Kb
    gemm_bt<<<dim3(2 * CDIM / 128, MTOT / 128), dim3(256), 0, stream>>>(
        x16, Wqt, bq, bk, Qb, MTOT, 2 * CDIM, CDIM, 5);
    // V projection, swapped operands: V^T layout out
    gemm_bt<<<dim3(MTOT / 128, CDIM / 128), dim3(256), 0, stream>>>(
        Wvt, x16, bv, nullptr, Vb, CDIM, MTOT, CDIM, 3);

    // attention (Kb = Qb + 16MB region, part index 64..127 of Qb layout)
    attn_kernel<<<dim3(BATCH * NHEAD * (SEQ / 128)), dim3(256), 0, stream>>>(
        Qb, Qb + (size_t)64 * SEQ * HDIM, Vb, (unsigned short*)Ctx);

    // output projection -> fp32 d_out
    gemm_bt<<<dim3(CDIM / 128, MTOT / 128), dim3(256), 0, stream>>>(
        Ctx, Wot, bo, nullptr, d_out, MTOT, CDIM, CDIM, 1);
}

// Round 3
// 348.852 us; speedup vs baseline: 2.8981x; 2.6481x over previous
//
#include <hip/hip_runtime.h>

// ---------------------------------------------------------------------------
// MaskedSelfAttention: B=4, T=2048, C=1024, H=16 heads, D=64, causal.
// cast x->bf16, transpose W->bf16, fused QKV proj (256^2-tile pipelined
// bf16 MFMA GEMM), double-buffered flash attention, output proj.
// ---------------------------------------------------------------------------

typedef __attribute__((ext_vector_type(8))) short bhalf8;   // 8 x bf16
typedef __attribute__((ext_vector_type(4))) float f32x4;

#define BATCH 4
#define SEQ 2048
#define CDIM 1024
#define NHEAD 16
#define HDIM 64
#define MTOT (BATCH * SEQ)   // 8192

static __device__ inline unsigned short f2bf(float f) {
    unsigned int u = __float_as_uint(f);
    unsigned int r = (u + 0x7fffu + ((u >> 16) & 1u)) >> 16;
    return (unsigned short)r;
}
static __device__ inline float bf2f(unsigned short u) {
    return __uint_as_float(((unsigned int)u) << 16);
}
static __device__ inline f32x4 zero4() {
    f32x4 z = {0.f, 0.f, 0.f, 0.f};
    return z;
}
static __device__ inline f32x4 MFMA(bhalf8 a, bhalf8 b, f32x4 c) {
    return __builtin_amdgcn_mfma_f32_16x16x32_bf16(a, b, c, 0, 0, 0);
}
static __device__ inline void gload16(const void* g, void* l) {
    __builtin_amdgcn_global_load_lds(
        (const __attribute__((address_space(1))) unsigned int*)g,
        (__attribute__((address_space(3))) unsigned int*)l, 16, 0, 0);
}

// ---------------------------------------------------------------------------
// cast x (fp32 [M][K]) -> bf16 (short) [M][K]
// ---------------------------------------------------------------------------
__global__ __launch_bounds__(256) void cast_x_kernel(const float* __restrict__ x,
                                                     short* __restrict__ o, int n8) {
    int i = blockIdx.x * 256 + threadIdx.x;
    if (i >= n8) return;
    const float4* xv = (const float4*)x;
    float4 a = xv[i * 2];
    float4 b = xv[i * 2 + 1];
    bhalf8 r;
    r[0] = (short)f2bf(a.x); r[1] = (short)f2bf(a.y);
    r[2] = (short)f2bf(a.z); r[3] = (short)f2bf(a.w);
    r[4] = (short)f2bf(b.x); r[5] = (short)f2bf(b.y);
    r[6] = (short)f2bf(b.z); r[7] = (short)f2bf(b.w);
    *(bhalf8*)(o + (size_t)i * 8) = r;
}

// ---------------------------------------------------------------------------
// transpose+cast 4 weight matrices: W fp32 [K][N] -> Wt bf16 [N][K]
// ---------------------------------------------------------------------------
__global__ __launch_bounds__(256) void wtrans_kernel(const float* __restrict__ W0,
                                                     const float* __restrict__ W1,
                                                     const float* __restrict__ W2,
                                                     const float* __restrict__ W3,
                                                     short* __restrict__ out) {
    __shared__ float t[32][33];
    const float* W = (blockIdx.z == 0) ? W0 : (blockIdx.z == 1) ? W1
                     : (blockIdx.z == 2) ? W2 : W3;
    short* o = out + (size_t)blockIdx.z * CDIM * CDIM;
    int n0 = blockIdx.x * 32, k0 = blockIdx.y * 32;
    int tx = threadIdx.x, ty = threadIdx.y;
    for (int j = 0; j < 4; ++j)
        t[ty + j * 8][tx] = W[(size_t)(k0 + ty + j * 8) * CDIM + n0 + tx];
    __syncthreads();
    for (int j = 0; j < 4; ++j)
        o[(size_t)(n0 + ty + j * 8) * CDIM + k0 + tx] = (short)f2bf(t[tx][ty + j * 8]);
}

// ---------------------------------------------------------------------------
// 256x256-tile GEMM, BK=32, K=1024, 512 threads (8 waves, 2x4), dbuf LDS,
// T3-min pipeline (stage t+1 before compute t, one barrier/iter).
// A [M][1024] bf16, Bt [N][1024] bf16 (row n = col n of B).
// Chunk swizzle: phys chunk p at row holds logical chunk p ^ ((row>>1)&3).
// MODE 0: fused QKV, GN=12 (nt 0-3 Q, 4-7 K, 8-11 V).
//         Q/K -> QKout [part][b][h][t][d] bf16 ; V -> Vout [b][h][d][t] bf16.
// MODE 1: O-proj, GN=4. fp32 out [M][1024] + bias.
// Epilogue staged through LDS for coalesced 16B stores.
// ---------------------------------------------------------------------------
template <int MODE, int GN>
__global__ __launch_bounds__(512) void gemm256(const short* __restrict__ A,
                                               const short* __restrict__ Bt,
                                               const float* __restrict__ b0,
                                               const float* __restrict__ b1,
                                               const float* __restrict__ b2,
                                               unsigned short* __restrict__ QKout,
                                               unsigned short* __restrict__ Vout,
                                               float* __restrict__ Fout) {
    __shared__ char lds[65536];   // Al: [0,32768) 2x16KB, Bl: [32768,65536)
    char* AlB0 = lds;
    char* BlB0 = lds + 32768;

    const int tid = threadIdx.x, lane = tid & 63, w = tid >> 6;
    const int g = lane >> 4, t16 = lane & 15;
    const int wr = w >> 2, wc = w & 3;

    // XCD-chunked grid swizzle: each XCD owns 4 consecutive m-tiles x all nt.
    const int f = blockIdx.x;
    const int xcd = f & 7, i = f >> 3;
    const int mt = xcd * 4 + i / GN, nt = i % GN;
    const int tm = mt * 256, tn = nt * 256;
    const int part = nt >> 2;   // MODE 0: 0=Q,1=K,2=V

    // staging coords (2 chunks per thread per matrix per iter)
    const int c0 = tid, c1 = 512 + tid;
    const int r0 = c0 >> 2, r1 = c1 >> 2;
    const int k0c = (c0 & 3) ^ ((r0 >> 1) & 3);
    const int k1c = (c1 & 3) ^ ((r1 >> 1) & 3);
    const short* a0 = A + (size_t)(tm + r0) * 1024 + k0c * 8;
    const short* a1 = A + (size_t)(tm + r1) * 1024 + k1c * 8;
    const short* bp0 = Bt + (size_t)(tn + r0) * 1024 + k0c * 8;
    const short* bp1 = Bt + (size_t)(tn + r1) * 1024 + k1c * 8;

    // fragment LDS byte offsets (within a 16KB buffer), precomputed
    int aoff[8], boff[4];
#pragma unroll
    for (int mi = 0; mi < 8; ++mi) {
        int row = wr * 128 + mi * 16 + t16;
        aoff[mi] = row * 64 + ((g ^ ((row >> 1) & 3)) << 4);
    }
#pragma unroll
    for (int ni = 0; ni < 4; ++ni) {
        int row = wc * 64 + ni * 16 + t16;
        boff[ni] = row * 64 + ((g ^ ((row >> 1) & 3)) << 4);
    }

    f32x4 acc[8][4];
#pragma unroll
    for (int mi = 0; mi < 8; ++mi)
#pragma unroll
        for (int ni = 0; ni < 4; ++ni) acc[mi][ni] = zero4();

#define STAGE(kt_, bb_)                                                   \
    do {                                                                  \
        int off_ = (kt_) * 32;                                            \
        char* al_ = AlB0 + (bb_) * 16384;                                 \
        char* bl_ = BlB0 + (bb_) * 16384;                                 \
        gload16(a0 + off_, al_ + w * 1024);                               \
        gload16(a1 + off_, al_ + 8192 + w * 1024);                        \
        gload16(bp0 + off_, bl_ + w * 1024);                              \
        gload16(bp1 + off_, bl_ + 8192 + w * 1024);                       \
    } while (0)

    STAGE(0, 0);
    __syncthreads();

#pragma unroll 2
    for (int kt = 0; kt < 32; ++kt) {
        const int buf = kt & 1;
        if (kt + 1 < 32) STAGE(kt + 1, buf ^ 1);
        const char* al = AlB0 + buf * 16384;
        const char* bl = BlB0 + buf * 16384;
        bhalf8 af[8], bfr[4];
#pragma unroll
        for (int mi = 0; mi < 8; ++mi) af[mi] = *(const bhalf8*)(al + aoff[mi]);
#pragma unroll
        for (int ni = 0; ni < 4; ++ni) bfr[ni] = *(const bhalf8*)(bl + boff[ni]);
#pragma unroll
        for (int mi = 0; mi < 8; ++mi)
#pragma unroll
            for (int ni = 0; ni < 4; ++ni)
                acc[mi][ni] = MFMA(af[mi], bfr[ni], acc[mi][ni]);
        __syncthreads();   // drains vmcnt(0): next tile staged; this buf free
    }
#undef STAGE

    // ------------------ epilogue via LDS (2 m-halves) ------------------
    for (int h = 0; h < 2; ++h) {
        if (h) __syncthreads();
        if (MODE == 0 && part == 2) {
            // V: LDS [n=256][m=128] bf16, swizzled 16B spans
            if (wr == h) {
#pragma unroll
                for (int mi = 0; mi < 8; ++mi)
#pragma unroll
                    for (int ni = 0; ni < 4; ++ni) {
                        int col = wc * 64 + ni * 16 + t16;        // n-local
                        float bias = b2[(tn + col) & 1023];
#pragma unroll
                        for (int r = 0; r < 4; ++r) {
                            int m_l = mi * 16 + g * 4 + r;        // 0..127
                            int byte = col * 256 + ((m_l * 2) ^ ((col & 7) << 4));
                            *(unsigned short*)(lds + byte) = f2bf(acc[mi][ni][r] + bias);
                        }
                    }
            }
            __syncthreads();
#pragma unroll
            for (int p = 0; p < 8; ++p) {
                int lin = p * 8192 + tid * 16;
                int rv = lin >> 8;                  // n-local 0..255
                int inrow = lin & 255;
                int phys = rv * 256 + (inrow ^ ((rv & 7) << 4));
                bhalf8 val = *(const bhalf8*)(lds + phys);
                int m0 = inrow >> 1;                // 0..127
                int n_g = tn + rv;
                int hh = (n_g & 1023) >> 6, d = n_g & 63;
                int m = tm + h * 128 + m0;
                int bi = m >> 11, t0 = m & 2047;
                *(bhalf8*)(Vout + (((size_t)((bi * NHEAD + hh) * HDIM + d)) << 11) + t0) = val;
            }
        } else {
            // Q/K or O: LDS [m=128][n=256] bf16, swizzled 32B spans
            if (wr == h) {
#pragma unroll
                for (int mi = 0; mi < 8; ++mi)
#pragma unroll
                    for (int ni = 0; ni < 4; ++ni) {
                        int col = wc * 64 + ni * 16 + t16;
                        float bias = 0.f;
                        if (MODE == 0) bias = (part == 0 ? b0 : b1)[(tn + col) & 1023];
#pragma unroll
                        for (int r = 0; r < 4; ++r) {
                            int row_l = mi * 16 + g * 4 + r;      // 0..127
                            int byte = row_l * 512 + ((col * 2) ^ (((row_l >> 2) & 3) << 5));
                            *(unsigned short*)(lds + byte) = f2bf(acc[mi][ni][r] + bias);
                        }
                    }
            }
            __syncthreads();
#pragma unroll
            for (int p = 0; p < 8; ++p) {
                int lin = p * 8192 + tid * 16;
                int row_l = lin >> 9;
                int inrow = lin & 511;
                int phys = row_l * 512 + ((inrow & ~31) ^ (((row_l >> 2) & 3) << 5)) + (inrow & 31);
                bhalf8 val = *(const bhalf8*)(lds + phys);
                int col0 = inrow >> 1;
                int n_g = tn + col0;
                int m = tm + h * 128 + row_l;
                if (MODE == 1) {
                    float* op = Fout + (size_t)m * 1024 + n_g;
                    float4 o0, o1;
                    o0.x = bf2f((unsigned short)val[0]) + b0[n_g + 0];
                    o0.y = bf2f((unsigned short)val[1]) + b0[n_g + 1];
                    o0.z = bf2f((unsigned short)val[2]) + b0[n_g + 2];
                    o0.w = bf2f((unsigned short)val[3]) + b0[n_g + 3];
                    o1.x = bf2f((unsigned short)val[4]) + b0[n_g + 4];
                    o1.y = bf2f((unsigned short)val[5]) + b0[n_g + 5];
                    o1.z = bf2f((unsigned short)val[6]) + b0[n_g + 6];
                    o1.w = bf2f((unsigned short)val[7]) + b0[n_g + 7];
                    *(float4*)(op) = o0;
                    *(float4*)(op + 4) = o1;
                } else {
                    int bi = m >> 11, t = m & 2047;
                    int hh = (n_g & 1023) >> 6, d0 = n_g & 63;
                    *(bhalf8*)(QKout +
                               (((size_t)((part * 64 + bi * NHEAD + hh) * SEQ + t)) << 6) + d0) = val;
                }
            }
        }
    }
}

// ---------------------------------------------------------------------------
// Flash attention, causal, double-buffered (unchanged from round 2).
// ---------------------------------------------------------------------------
__global__ __launch_bounds__(256) void attn_kernel(const short* __restrict__ Q,
                                                   const short* __restrict__ K,
                                                   const short* __restrict__ V,
                                                   unsigned short* __restrict__ ctx) {
    __shared__ short Kl[2][64 * 64];
    __shared__ short Vl[2][64 * 64];
    __shared__ short Pl[4][32 * 64];

    const int tid = threadIdx.x, lane = tid & 63, w = tid >> 6;
    const int g = lane >> 4, t16 = lane & 15;

    int orig = blockIdx.x;
    int swz = (orig & 7) * 128 + (orig >> 3);
    const int bh = swz >> 4;
    const int qti = 15 - (swz & 15);
    const int qbase = qti * 128;
    const int nt = 2 * qti + 2;

    const short* Qh = Q + ((size_t)bh << 17);
    const short* Kh = K + ((size_t)bh << 17);
    const short* Vh = V + ((size_t)bh << 17);

    bhalf8 qf[2][2];
    for (int rf = 0; rf < 2; ++rf) {
        const short* qp = Qh + ((size_t)(qbase + w * 32 + rf * 16 + t16) << 6) + g * 8;
        qf[rf][0] = *(const bhalf8*)(qp);
        qf[rf][1] = *(const bhalf8*)(qp + 32);
    }

    f32x4 acc[2][4];
    for (int rf = 0; rf < 2; ++rf)
        for (int i = 0; i < 4; ++i) acc[rf][i] = zero4();
    float mrow[2][4], lrow[2][4];
    for (int rf = 0; rf < 2; ++rf)
        for (int r = 0; r < 4; ++r) { mrow[rf][r] = -1e30f; lrow[rf][r] = 0.f; }
    const float SC = 0.125f * 1.4426950408889634f;

#define STAGE(kv_, bb_)                                                          \
    do {                                                                         \
        for (int it = 0; it < 2; ++it) {                                         \
            int c = it * 256 + tid;                                              \
            int s = c >> 3;                                                      \
            int dc = (c & 7) ^ (s & 7);                                          \
            gload16(Kh + ((size_t)((kv_) * 64 + s) << 6) + dc * 8,               \
                    (char*)Kl[bb_] + it * 4096 + w * 1024);                      \
            int sc2 = (c & 7) ^ (s & 7);                                         \
            gload16(Vh + ((size_t)s << 11) + (kv_) * 64 + sc2 * 8,               \
                    (char*)Vl[bb_] + it * 4096 + w * 1024);                      \
        }                                                                        \
    } while (0)

    STAGE(0, 0);
    __syncthreads();

    int buf = 0;
    for (int kv = 0; kv < nt; ++kv) {
        if (kv + 1 < nt) STAGE(kv + 1, buf ^ 1);

        f32x4 lg[2][4];
#pragma unroll
        for (int cb = 0; cb < 4; ++cb) {
            int s = cb * 16 + t16;
            int sw = (s & 7) << 4;
            const char* rowp = (const char*)Kl[buf] + s * 128;
            bhalf8 k0 = *(const bhalf8*)(rowp + ((g * 16) ^ sw));
            bhalf8 k1 = *(const bhalf8*)(rowp + ((64 + g * 16) ^ sw));
#pragma unroll
            for (int rf = 0; rf < 2; ++rf) {
                f32x4 z = zero4();
                z = MFMA(qf[rf][0], k0, z);
                z = MFMA(qf[rf][1], k1, z);
                lg[rf][cb] = z;
            }
        }

        float p[2][4][4];
        bool domask = (kv >= 2 * qti);
#pragma unroll
        for (int rf = 0; rf < 2; ++rf)
#pragma unroll
            for (int cb = 0; cb < 4; ++cb) {
                int col = kv * 64 + cb * 16 + t16;
#pragma unroll
                for (int r = 0; r < 4; ++r) {
                    int row = qbase + w * 32 + rf * 16 + g * 4 + r;
                    float v = lg[rf][cb][r] * SC;
                    p[rf][cb][r] = (domask && col > row) ? -1e30f : v;
                }
            }

#pragma unroll
        for (int rf = 0; rf < 2; ++rf) {
            float corr[4];
#pragma unroll
            for (int r = 0; r < 4; ++r) {
                float tmax = fmaxf(fmaxf(p[rf][0][r], p[rf][1][r]),
                                   fmaxf(p[rf][2][r], p[rf][3][r]));
                for (int off = 1; off < 16; off <<= 1)
                    tmax = fmaxf(tmax, __shfl_xor(tmax, off, 64));
                float mnew = fmaxf(mrow[rf][r], tmax);
                corr[r] = exp2f(mrow[rf][r] - mnew);
                mrow[rf][r] = mnew;
            }
#pragma unroll
            for (int r = 0; r < 4; ++r) {
                float s4 = 0.f;
#pragma unroll
                for (int cb = 0; cb < 4; ++cb) {
                    p[rf][cb][r] = exp2f(p[rf][cb][r] - mrow[rf][r]);
                    s4 += p[rf][cb][r];
                }
                for (int off = 1; off < 16; off <<= 1)
                    s4 += __shfl_xor(s4, off, 64);
                lrow[rf][r] = lrow[rf][r] * corr[r] + s4;
            }
#pragma unroll
            for (int i = 0; i < 4; ++i)
#pragma unroll
                for (int r = 0; r < 4; ++r) acc[rf][i][r] *= corr[r];
        }

#pragma unroll
        for (int rf = 0; rf < 2; ++rf)
#pragma unroll
            for (int cb = 0; cb < 4; ++cb)
#pragma unroll
                for (int r = 0; r < 4; ++r) {
                    int lr = rf * 16 + g * 4 + r;
                    int byte = (lr * 128 + (cb * 16 + t16) * 2) ^ ((lr & 7) << 4);
                    *(unsigned short*)((char*)Pl[w] + byte) = f2bf(p[rf][cb][r]);
                }

#pragma unroll
        for (int kk = 0; kk < 2; ++kk) {
            bhalf8 vf[4];
#pragma unroll
            for (int db = 0; db < 4; ++db) {
                int d = db * 16 + t16;
                int vbyte = d * 128 + ((kk * 64 + g * 16) ^ ((d & 7) << 4));
                vf[db] = *(const bhalf8*)((const char*)Vl[buf] + vbyte);
            }
#pragma unroll
            for (int rf = 0; rf < 2; ++rf) {
                int lr2 = rf * 16 + t16;
                int abyte = (lr2 * 128 + kk * 64 + g * 16) ^ ((lr2 & 7) << 4);
                bhalf8 pa = *(const bhalf8*)((const char*)Pl[w] + abyte);
#pragma unroll
                for (int db = 0; db < 4; ++db)
                    acc[rf][db] = MFMA(pa, vf[db], acc[rf][db]);
            }
        }

        __syncthreads();
        buf ^= 1;
    }
#undef STAGE

    int b = bh >> 4, h = bh & 15;
#pragma unroll
    for (int rf = 0; rf < 2; ++rf)
#pragma unroll
        for (int r = 0; r < 4; ++r) {
            float inv = 1.f / lrow[rf][r];
            int t = qbase + w * 32 + rf * 16 + g * 4 + r;
            size_t rowoff = (((size_t)(b * SEQ + t)) << 10) + h * 64;
#pragma unroll
            for (int db = 0; db < 4; ++db)
                ctx[rowoff + db * 16 + t16] = f2bf(acc[rf][db][r] * inv);
        }
}

// ---------------------------------------------------------------------------
// launch
// ---------------------------------------------------------------------------
extern "C" void kernel_launch(void* const* d_in, const int* in_sizes, int n_in,
                              void* d_out, int out_size, void* d_ws, size_t ws_size,
                              hipStream_t stream) {
    const float* x  = (const float*)d_in[0];
    const float* Wq = (const float*)d_in[1];
    const float* bq = (const float*)d_in[2];
    const float* Wk = (const float*)d_in[3];
    const float* bk = (const float*)d_in[4];
    const float* Wv = (const float*)d_in[5];
    const float* bv = (const float*)d_in[6];
    const float* Wo = (const float*)d_in[7];
    const float* bo = (const float*)d_in[8];

    char* ws = (char*)d_ws;
    short* x16 = (short*)(ws);                                // 16 MB
    short* Wt  = (short*)(ws + (size_t)16 * 1024 * 1024);     // q,k,v,o 2MB each
    short* Wot = Wt + (size_t)3 * CDIM * CDIM;
    short* Qb  = (short*)(ws + (size_t)24 * 1024 * 1024);     // 32 MB Q||K
    short* Vb  = (short*)(ws + (size_t)56 * 1024 * 1024);     // 16 MB [BH][D][T]
    short* Ctx = (short*)(ws + (size_t)72 * 1024 * 1024);     // 16 MB [M][C]

    cast_x_kernel<<<dim3(MTOT * CDIM / 8 / 256), dim3(256), 0, stream>>>(
        x, x16, MTOT * CDIM / 8);
    wtrans_kernel<<<dim3(32, 32, 4), dim3(32, 8), 0, stream>>>(Wq, Wk, Wv, Wo, Wt);

    // fused QKV projection: N = 3072 (Wq||Wk||Wv rows), 384 blocks
    gemm256<0, 12><<<dim3(384), dim3(512), 0, stream>>>(
        x16, Wt, bq, bk, bv, (unsigned short*)Qb, (unsigned short*)Vb, nullptr);

    // attention (K part = Qb + 64*SEQ*HDIM)
    attn_kernel<<<dim3(BATCH * NHEAD * (SEQ / 128)), dim3(256), 0, stream>>>(
        Qb, Qb + (size_t)64 * SEQ * HDIM, Vb, (unsigned short*)Ctx);

    // output projection -> fp32 d_out, 128 blocks
    gemm256<1, 4><<<dim3(128), dim3(512), 0, stream>>>(
        Ctx, Wot, bo, nullptr, nullptr, nullptr, nullptr, (float*)d_out);
}

// Round 5
// 251.935 us; speedup vs baseline: 4.0130x; 1.3847x over previous
//
#include <hip/hip_runtime.h>
#include <hip/hip_bf16.h>

// ---------------------------------------------------------------------------
// MaskedSelfAttention: B=4, T=2048, C=1024, H=16 heads, D=64, causal.
// cast x->bf16, transpose W->bf16, fused QKV proj (256^2-tile pipelined
// bf16 MFMA GEMM, Q pre-scaled by 1/sqrt(D)*log2e), flash attention with
// swapped QK^T + in-register softmax + defer-max, output proj.
// ---------------------------------------------------------------------------

typedef __attribute__((ext_vector_type(8))) short bhalf8;   // 8 x bf16
typedef __attribute__((ext_vector_type(4))) float f32x4;

#define BATCH 4
#define SEQ 2048
#define CDIM 1024
#define NHEAD 16
#define HDIM 64
#define MTOT (BATCH * SEQ)   // 8192
#define QSCALE 0.18033688011112042f   // 1/sqrt(64) * log2(e)

static __device__ inline unsigned short f2bf(float f) {
    unsigned int u = __float_as_uint(f);
    unsigned int r = (u + 0x7fffu + ((u >> 16) & 1u)) >> 16;
    return (unsigned short)r;
}
static __device__ inline float bf2f(unsigned short u) {
    return __uint_as_float(((unsigned int)u) << 16);
}
static __device__ inline f32x4 zero4() {
    f32x4 z = {0.f, 0.f, 0.f, 0.f};
    return z;
}
static __device__ inline f32x4 MFMA(bhalf8 a, bhalf8 b, f32x4 c) {
    return __builtin_amdgcn_mfma_f32_16x16x32_bf16(a, b, c, 0, 0, 0);
}
static __device__ inline void gload16(const void* g, void* l) {
    __builtin_amdgcn_global_load_lds(
        (const __attribute__((address_space(1))) unsigned int*)g,
        (__attribute__((address_space(3))) unsigned int*)l, 16, 0, 0);
}
static __device__ inline unsigned int pkbf16(float lo, float hi) {
    union { __hip_bfloat162 h; unsigned int u; } c;
    c.h = __float22bfloat162_rn(make_float2(lo, hi));
    return c.u;
}

// ---------------------------------------------------------------------------
// cast x (fp32 [M][K]) -> bf16 (short) [M][K]
// ---------------------------------------------------------------------------
__global__ __launch_bounds__(256) void cast_x_kernel(const float* __restrict__ x,
                                                     short* __restrict__ o, int n8) {
    int i = blockIdx.x * 256 + threadIdx.x;
    if (i >= n8) return;
    const float4* xv = (const float4*)x;
    float4 a = xv[i * 2];
    float4 b = xv[i * 2 + 1];
    bhalf8 r;
    r[0] = (short)f2bf(a.x); r[1] = (short)f2bf(a.y);
    r[2] = (short)f2bf(a.z); r[3] = (short)f2bf(a.w);
    r[4] = (short)f2bf(b.x); r[5] = (short)f2bf(b.y);
    r[6] = (short)f2bf(b.z); r[7] = (short)f2bf(b.w);
    *(bhalf8*)(o + (size_t)i * 8) = r;
}

// ---------------------------------------------------------------------------
// transpose+cast 4 weight matrices: W fp32 [K][N] -> Wt bf16 [N][K]
// ---------------------------------------------------------------------------
__global__ __launch_bounds__(256) void wtrans_kernel(const float* __restrict__ W0,
                                                     const float* __restrict__ W1,
                                                     const float* __restrict__ W2,
                                                     const float* __restrict__ W3,
                                                     short* __restrict__ out) {
    __shared__ float t[32][33];
    const float* W = (blockIdx.z == 0) ? W0 : (blockIdx.z == 1) ? W1
                     : (blockIdx.z == 2) ? W2 : W3;
    short* o = out + (size_t)blockIdx.z * CDIM * CDIM;
    int n0 = blockIdx.x * 32, k0 = blockIdx.y * 32;
    int tx = threadIdx.x, ty = threadIdx.y;
    for (int j = 0; j < 4; ++j)
        t[ty + j * 8][tx] = W[(size_t)(k0 + ty + j * 8) * CDIM + n0 + tx];
    __syncthreads();
    for (int j = 0; j < 4; ++j)
        o[(size_t)(n0 + ty + j * 8) * CDIM + k0 + tx] = (short)f2bf(t[tx][ty + j * 8]);
}

// ---------------------------------------------------------------------------
// 256x256-tile GEMM, BK=32, K=1024, 512 threads (8 waves, 2x4), dbuf LDS,
// T3-min pipeline. MODE 0: fused QKV (Q scaled by QSCALE); MODE 1: O-proj.
// ---------------------------------------------------------------------------
template <int MODE, int GN>
__global__ __launch_bounds__(512) void gemm256(const short* __restrict__ A,
                                               const short* __restrict__ Bt,
                                               const float* __restrict__ b0,
                                               const float* __restrict__ b1,
                                               const float* __restrict__ b2,
                                               unsigned short* __restrict__ QKout,
                                               unsigned short* __restrict__ Vout,
                                               float* __restrict__ Fout) {
    __shared__ char lds[65536];
    char* AlB0 = lds;
    char* BlB0 = lds + 32768;

    const int tid = threadIdx.x, lane = tid & 63, w = tid >> 6;
    const int g = lane >> 4, t16 = lane & 15;
    const int wr = w >> 2, wc = w & 3;

    const int f = blockIdx.x;
    const int xcd = f & 7, i = f >> 3;
    const int mt = xcd * 4 + i / GN, nt = i % GN;
    const int tm = mt * 256, tn = nt * 256;
    const int part = nt >> 2;

    const int c0 = tid, c1 = 512 + tid;
    const int r0 = c0 >> 2, r1 = c1 >> 2;
    const int k0c = (c0 & 3) ^ ((r0 >> 1) & 3);
    const int k1c = (c1 & 3) ^ ((r1 >> 1) & 3);
    const short* a0 = A + (size_t)(tm + r0) * 1024 + k0c * 8;
    const short* a1 = A + (size_t)(tm + r1) * 1024 + k1c * 8;
    const short* bp0 = Bt + (size_t)(tn + r0) * 1024 + k0c * 8;
    const short* bp1 = Bt + (size_t)(tn + r1) * 1024 + k1c * 8;

    int aoff[8], boff[4];
#pragma unroll
    for (int mi = 0; mi < 8; ++mi) {
        int row = wr * 128 + mi * 16 + t16;
        aoff[mi] = row * 64 + ((g ^ ((row >> 1) & 3)) << 4);
    }
#pragma unroll
    for (int ni = 0; ni < 4; ++ni) {
        int row = wc * 64 + ni * 16 + t16;
        boff[ni] = row * 64 + ((g ^ ((row >> 1) & 3)) << 4);
    }

    f32x4 acc[8][4];
#pragma unroll
    for (int mi = 0; mi < 8; ++mi)
#pragma unroll
        for (int ni = 0; ni < 4; ++ni) acc[mi][ni] = zero4();

#define STAGE(kt_, bb_)                                                   \
    do {                                                                  \
        int off_ = (kt_) * 32;                                            \
        char* al_ = AlB0 + (bb_) * 16384;                                 \
        char* bl_ = BlB0 + (bb_) * 16384;                                 \
        gload16(a0 + off_, al_ + w * 1024);                               \
        gload16(a1 + off_, al_ + 8192 + w * 1024);                        \
        gload16(bp0 + off_, bl_ + w * 1024);                              \
        gload16(bp1 + off_, bl_ + 8192 + w * 1024);                       \
    } while (0)

    STAGE(0, 0);
    __syncthreads();

#pragma unroll 2
    for (int kt = 0; kt < 32; ++kt) {
        const int buf = kt & 1;
        if (kt + 1 < 32) STAGE(kt + 1, buf ^ 1);
        const char* al = AlB0 + buf * 16384;
        const char* bl = BlB0 + buf * 16384;
        bhalf8 af[8], bfr[4];
#pragma unroll
        for (int mi = 0; mi < 8; ++mi) af[mi] = *(const bhalf8*)(al + aoff[mi]);
#pragma unroll
        for (int ni = 0; ni < 4; ++ni) bfr[ni] = *(const bhalf8*)(bl + boff[ni]);
        __builtin_amdgcn_s_setprio(1);
#pragma unroll
        for (int mi = 0; mi < 8; ++mi)
#pragma unroll
            for (int ni = 0; ni < 4; ++ni)
                acc[mi][ni] = MFMA(af[mi], bfr[ni], acc[mi][ni]);
        __builtin_amdgcn_s_setprio(0);
        __syncthreads();
    }
#undef STAGE

    // ------------------ epilogue via LDS (2 m-halves) ------------------
    for (int h = 0; h < 2; ++h) {
        if (h) __syncthreads();
        if (MODE == 0 && part == 2) {
            if (wr == h) {
#pragma unroll
                for (int mi = 0; mi < 8; ++mi)
#pragma unroll
                    for (int ni = 0; ni < 4; ++ni) {
                        int col = wc * 64 + ni * 16 + t16;
                        float bias = b2[(tn + col) & 1023];
#pragma unroll
                        for (int r = 0; r < 4; ++r) {
                            int m_l = mi * 16 + g * 4 + r;
                            int byte = col * 256 + ((m_l * 2) ^ ((col & 7) << 4));
                            *(unsigned short*)(lds + byte) = f2bf(acc[mi][ni][r] + bias);
                        }
                    }
            }
            __syncthreads();
#pragma unroll
            for (int p = 0; p < 8; ++p) {
                int lin = p * 8192 + tid * 16;
                int rv = lin >> 8;
                int inrow = lin & 255;
                int phys = rv * 256 + (inrow ^ ((rv & 7) << 4));
                bhalf8 val = *(const bhalf8*)(lds + phys);
                int m0 = inrow >> 1;
                int n_g = tn + rv;
                int hh = (n_g & 1023) >> 6, d = n_g & 63;
                int m = tm + h * 128 + m0;
                int bi = m >> 11, t0 = m & 2047;
                *(bhalf8*)(Vout + (((size_t)((bi * NHEAD + hh) * HDIM + d)) << 11) + t0) = val;
            }
        } else {
            if (wr == h) {
#pragma unroll
                for (int mi = 0; mi < 8; ++mi)
#pragma unroll
                    for (int ni = 0; ni < 4; ++ni) {
                        int col = wc * 64 + ni * 16 + t16;
                        float bias = 0.f;
                        if (MODE == 0) bias = (part == 0 ? b0 : b1)[(tn + col) & 1023];
#pragma unroll
                        for (int r = 0; r < 4; ++r) {
                            int row_l = mi * 16 + g * 4 + r;
                            float v = acc[mi][ni][r] + bias;
                            if (MODE == 0 && part == 0) v *= QSCALE;
                            int byte = row_l * 512 + ((col * 2) ^ (((row_l >> 2) & 3) << 5));
                            *(unsigned short*)(lds + byte) = f2bf(v);
                        }
                    }
            }
            __syncthreads();
#pragma unroll
            for (int p = 0; p < 8; ++p) {
                int lin = p * 8192 + tid * 16;
                int row_l = lin >> 9;
                int inrow = lin & 511;
                int phys = row_l * 512 + ((inrow & ~31) ^ (((row_l >> 2) & 3) << 5)) + (inrow & 31);
                bhalf8 val = *(const bhalf8*)(lds + phys);
                int col0 = inrow >> 1;
                int n_g = tn + col0;
                int m = tm + h * 128 + row_l;
                if (MODE == 1) {
                    float* op = Fout + (size_t)m * 1024 + n_g;
                    float4 o0, o1;
                    o0.x = bf2f((unsigned short)val[0]) + b0[n_g + 0];
                    o0.y = bf2f((unsigned short)val[1]) + b0[n_g + 1];
                    o0.z = bf2f((unsigned short)val[2]) + b0[n_g + 2];
                    o0.w = bf2f((unsigned short)val[3]) + b0[n_g + 3];
                    o1.x = bf2f((unsigned short)val[4]) + b0[n_g + 4];
                    o1.y = bf2f((unsigned short)val[5]) + b0[n_g + 5];
                    o1.z = bf2f((unsigned short)val[6]) + b0[n_g + 6];
                    o1.w = bf2f((unsigned short)val[7]) + b0[n_g + 7];
                    *(float4*)(op) = o0;
                    *(float4*)(op + 4) = o1;
                } else {
                    int bi = m >> 11, t = m & 2047;
                    int hh = (n_g & 1023) >> 6, d0 = n_g & 63;
                    *(bhalf8*)(QKout +
                               (((size_t)((part * 64 + bi * NHEAD + hh) * SEQ + t)) << 6) + d0) = val;
                }
            }
        }
    }
}

// ---------------------------------------------------------------------------
// Flash attention, causal, double-buffered, swapped QK^T + in-register softmax.
// 4 waves per block; each wave owns 32 q-rows (QBLK=128). KV tile = 64.
// Q pre-scaled by QSCALE (log2 domain). Softmax state in t16-layout
// (q = nf*16+t16); PV accumulator in g-layout (q = rf*16+g*4+r); corr/linv
// cross layouts via per-lane __shfl broadcast (rare with defer-max THR=8).
// ---------------------------------------------------------------------------
__global__ __launch_bounds__(256) void attn_kernel(const short* __restrict__ Q,
                                                   const short* __restrict__ K,
                                                   const short* __restrict__ V,
                                                   unsigned short* __restrict__ ctx) {
    __shared__ short Kl[2][64 * 64];
    __shared__ short Vl[2][64 * 64];
    __shared__ short Pl[4][32 * 64];

    const int tid = threadIdx.x, lane = tid & 63, w = tid >> 6;
    const int g = lane >> 4, t16 = lane & 15;

    int orig = blockIdx.x;
    int swz = (orig & 7) * 128 + (orig >> 3);
    const int bh = swz >> 4;
    const int qti = 15 - (swz & 15);
    const int qbase = qti * 128;
    const int nt = 2 * qti + 2;

    const short* Qh = Q + ((size_t)bh << 17);
    const short* Kh = K + ((size_t)bh << 17);
    const short* Vh = V + ((size_t)bh << 17);

    // Q B-frags: col=t16 -> q = qbase + w*32 + nf*16 + t16; k = kk*32+g*8+j
    bhalf8 qf[2][2];
#pragma unroll
    for (int nf = 0; nf < 2; ++nf) {
        const short* qp = Qh + ((size_t)(qbase + w * 32 + nf * 16 + t16) << 6) + g * 8;
        qf[nf][0] = *(const bhalf8*)(qp);
        qf[nf][1] = *(const bhalf8*)(qp + 32);
    }

    f32x4 acc[2][4];   // [rf][db]: q = rf*16+g*4+r, d = db*16+t16
#pragma unroll
    for (int rf = 0; rf < 2; ++rf)
#pragma unroll
        for (int i = 0; i < 4; ++i) acc[rf][i] = zero4();
    float m[2], l[2];  // t16-layout
    m[0] = m[1] = -1e30f;
    l[0] = l[1] = 0.f;

#define STAGE(kv_, bb_)                                                          \
    do {                                                                         \
        for (int it = 0; it < 2; ++it) {                                         \
            int c = it * 256 + tid;                                              \
            int s = c >> 3;                                                      \
            int dc = (c & 7) ^ (s & 7);                                          \
            gload16(Kh + ((size_t)((kv_) * 64 + s) << 6) + dc * 8,               \
                    (char*)Kl[bb_] + it * 4096 + w * 1024);                      \
            int sc2 = (c & 7) ^ (s & 7);                                         \
            gload16(Vh + ((size_t)s << 11) + (kv_) * 64 + sc2 * 8,               \
                    (char*)Vl[bb_] + it * 4096 + w * 1024);                      \
        }                                                                        \
    } while (0)

    STAGE(0, 0);
    __syncthreads();

    int buf = 0;
    for (int kv = 0; kv < nt; ++kv) {
        if (kv + 1 < nt) STAGE(kv + 1, buf ^ 1);

        // ---- QK^T (swapped): S^T[key][q], lg[nf][cb], key=cb*16+g*4+r ----
        f32x4 lg[2][4];
        __builtin_amdgcn_s_setprio(1);
#pragma unroll
        for (int cb = 0; cb < 4; ++cb) {
            int s = cb * 16 + t16;
            int sw = (s & 7) << 4;
            const char* rowp = (const char*)Kl[buf] + s * 128;
            bhalf8 k0 = *(const bhalf8*)(rowp + ((g * 16) ^ sw));
            bhalf8 k1 = *(const bhalf8*)(rowp + ((64 + g * 16) ^ sw));
#pragma unroll
            for (int nf = 0; nf < 2; ++nf) {
                f32x4 z = zero4();
                z = MFMA(k0, qf[nf][0], z);
                z = MFMA(k1, qf[nf][1], z);
                lg[nf][cb] = z;
            }
        }
        __builtin_amdgcn_s_setprio(0);

        // ---- causal mask (diag tiles only; log2 domain already) ----
        if (kv >= 2 * qti) {
#pragma unroll
            for (int nf = 0; nf < 2; ++nf) {
                int row = qbase + w * 32 + nf * 16 + t16;
#pragma unroll
                for (int cb = 0; cb < 4; ++cb) {
                    int key0 = kv * 64 + cb * 16 + g * 4;
#pragma unroll
                    for (int r = 0; r < 4; ++r)
                        if (key0 + r > row) lg[nf][cb][r] = -1e30f;
                }
            }
        }

        // ---- in-lane row max + cross-g reduce (2 shfl per nf) ----
        float pm[2];
#pragma unroll
        for (int nf = 0; nf < 2; ++nf) {
            float a = fmaxf(fmaxf(lg[nf][0][0], lg[nf][0][1]),
                            fmaxf(lg[nf][0][2], lg[nf][0][3]));
            float b = fmaxf(fmaxf(lg[nf][1][0], lg[nf][1][1]),
                            fmaxf(lg[nf][1][2], lg[nf][1][3]));
            float c = fmaxf(fmaxf(lg[nf][2][0], lg[nf][2][1]),
                            fmaxf(lg[nf][2][2], lg[nf][2][3]));
            float d = fmaxf(fmaxf(lg[nf][3][0], lg[nf][3][1]),
                            fmaxf(lg[nf][3][2], lg[nf][3][3]));
            float t = fmaxf(fmaxf(a, b), fmaxf(c, d));
            t = fmaxf(t, __shfl_xor(t, 16, 64));
            t = fmaxf(t, __shfl_xor(t, 32, 64));
            pm[nf] = t;
        }

        // ---- defer-max: rescale only when max grew past THR=8 ----
        bool need = (pm[0] > m[0] + 8.f) || (pm[1] > m[1] + 8.f);
        if (__any(need)) {
            float corr[2];
#pragma unroll
            for (int nf = 0; nf < 2; ++nf) {
                float mn = fmaxf(m[nf], pm[nf]);
                corr[nf] = exp2f(m[nf] - mn);
                m[nf] = mn;
                l[nf] *= corr[nf];
            }
#pragma unroll
            for (int rf = 0; rf < 2; ++rf)
#pragma unroll
                for (int r = 0; r < 4; ++r) {
                    float c = __shfl(corr[rf], g * 4 + r, 64);
#pragma unroll
                    for (int db = 0; db < 4; ++db) acc[rf][db][r] *= c;
                }
        }

        // ---- exp2 + partial l + pack + LDS write (8 x ds_write_b64) ----
#pragma unroll
        for (int nf = 0; nf < 2; ++nf) {
            float s_ = 0.f;
            int rowbyte = (nf * 16 + t16) * 128;
            int swb = (t16 & 7) << 4;
#pragma unroll
            for (int cb = 0; cb < 4; ++cb) {
                float e0 = exp2f(lg[nf][cb][0] - m[nf]);
                float e1 = exp2f(lg[nf][cb][1] - m[nf]);
                float e2 = exp2f(lg[nf][cb][2] - m[nf]);
                float e3 = exp2f(lg[nf][cb][3] - m[nf]);
                s_ += (e0 + e1) + (e2 + e3);
                uint2 wv;
                wv.x = pkbf16(e0, e1);
                wv.y = pkbf16(e2, e3);
                int byte = (rowbyte + cb * 32 + g * 8) ^ swb;
                *(uint2*)((char*)Pl[w] + byte) = wv;
            }
            l[nf] += s_;
        }

        // ---- PV: acc += P @ V ----
        __builtin_amdgcn_s_setprio(1);
#pragma unroll
        for (int kk = 0; kk < 2; ++kk) {
            bhalf8 vf[4];
#pragma unroll
            for (int db = 0; db < 4; ++db) {
                int d = db * 16 + t16;
                int vbyte = d * 128 + ((kk * 64 + g * 16) ^ ((d & 7) << 4));
                vf[db] = *(const bhalf8*)((const char*)Vl[buf] + vbyte);
            }
#pragma unroll
            for (int rf = 0; rf < 2; ++rf) {
                int lr2 = rf * 16 + t16;
                int abyte = (lr2 * 128 + kk * 64 + g * 16) ^ ((lr2 & 7) << 4);
                bhalf8 pa = *(const bhalf8*)((const char*)Pl[w] + abyte);
#pragma unroll
                for (int db = 0; db < 4; ++db)
                    acc[rf][db] = MFMA(pa, vf[db], acc[rf][db]);
            }
        }
        __builtin_amdgcn_s_setprio(0);

        __syncthreads();
        buf ^= 1;
    }
#undef STAGE

    // ---- finalize l (2 shfl), broadcast 1/l to g-layout, write ctx ----
    float linv[2];
#pragma unroll
    for (int nf = 0; nf < 2; ++nf) {
        float t = l[nf];
        t += __shfl_xor(t, 16, 64);
        t += __shfl_xor(t, 32, 64);
        linv[nf] = 1.f / t;
    }
    int b = bh >> 4, h = bh & 15;
#pragma unroll
    for (int rf = 0; rf < 2; ++rf)
#pragma unroll
        for (int r = 0; r < 4; ++r) {
            float inv = __shfl(linv[rf], g * 4 + r, 64);
            int t = qbase + w * 32 + rf * 16 + g * 4 + r;
            size_t rowoff = (((size_t)(b * SEQ + t)) << 10) + h * 64;
#pragma unroll
            for (int db = 0; db < 4; ++db)
                ctx[rowoff + db * 16 + t16] = f2bf(acc[rf][db][r] * inv);
        }
}

// ---------------------------------------------------------------------------
// launch
// ---------------------------------------------------------------------------
extern "C" void kernel_launch(void* const* d_in, const int* in_sizes, int n_in,
                              void* d_out, int out_size, void* d_ws, size_t ws_size,
                              hipStream_t stream) {
    const float* x  = (const float*)d_in[0];
    const float* Wq = (const float*)d_in[1];
    const float* bq = (const float*)d_in[2];
    const float* Wk = (const float*)d_in[3];
    const float* bk = (const float*)d_in[4];
    const float* Wv = (const float*)d_in[5];
    const float* bv = (const float*)d_in[6];
    const float* Wo = (const float*)d_in[7];
    const float* bo = (const float*)d_in[8];

    char* ws = (char*)d_ws;
    short* x16 = (short*)(ws);                                // 16 MB
    short* Wt  = (short*)(ws + (size_t)16 * 1024 * 1024);     // q,k,v,o 2MB each
    short* Wot = Wt + (size_t)3 * CDIM * CDIM;
    short* Qb  = (short*)(ws + (size_t)24 * 1024 * 1024);     // 32 MB Q||K
    short* Vb  = (short*)(ws + (size_t)56 * 1024 * 1024);     // 16 MB [BH][D][T]
    short* Ctx = (short*)(ws + (size_t)72 * 1024 * 1024);     // 16 MB [M][C]

    cast_x_kernel<<<dim3(MTOT * CDIM / 8 / 256), dim3(256), 0, stream>>>(
        x, x16, MTOT * CDIM / 8);
    wtrans_kernel<<<dim3(32, 32, 4), dim3(32, 8), 0, stream>>>(Wq, Wk, Wv, Wo, Wt);

    // fused QKV projection: N = 3072 (Wq||Wk||Wv rows), 384 blocks
    gemm256<0, 12><<<dim3(384), dim3(512), 0, stream>>>(
        x16, Wt, bq, bk, bv, (unsigned short*)Qb, (unsigned short*)Vb, nullptr);

    // attention (K part = Qb + 64*SEQ*HDIM)
    attn_kernel<<<dim3(BATCH * NHEAD * (SEQ / 128)), dim3(256), 0, stream>>>(
        Qb, Qb + (size_t)64 * SEQ * HDIM, Vb, (unsigned short*)Ctx);

    // output projection -> fp32 d_out, 128 blocks
    gemm256<1, 4><<<dim3(128), dim3(512), 0, stream>>>(
        Ctx, Wot, bo, nullptr, nullptr, nullptr, nullptr, (float*)d_out);
}

// Round 6
// 213.554 us; speedup vs baseline: 4.7343x; 1.1797x over previous
//
#include <hip/hip_runtime.h>
#include <hip/hip_bf16.h>

// ---------------------------------------------------------------------------
// MaskedSelfAttention: B=4, T=2048, C=1024, H=16 heads, D=64, causal.
// cast x->bf16, transpose W->bf16, fused QKV proj (256^2-tile pipelined
// bf16 MFMA GEMM, Q pre-scaled by 1/sqrt(D)*log2e), flash attention with
// swapped QK^T + in-register softmax + defer-max + paired q-tiles for
// causal load balance, output proj.
// ---------------------------------------------------------------------------

typedef __attribute__((ext_vector_type(8))) short bhalf8;   // 8 x bf16
typedef __attribute__((ext_vector_type(4))) float f32x4;

#define BATCH 4
#define SEQ 2048
#define CDIM 1024
#define NHEAD 16
#define HDIM 64
#define MTOT (BATCH * SEQ)   // 8192
#define QSCALE 0.18033688011112042f   // 1/sqrt(64) * log2(e)

static __device__ inline unsigned short f2bf(float f) {
    unsigned int u = __float_as_uint(f);
    unsigned int r = (u + 0x7fffu + ((u >> 16) & 1u)) >> 16;
    return (unsigned short)r;
}
static __device__ inline float bf2f(unsigned short u) {
    return __uint_as_float(((unsigned int)u) << 16);
}
static __device__ inline f32x4 zero4() {
    f32x4 z = {0.f, 0.f, 0.f, 0.f};
    return z;
}
static __device__ inline f32x4 MFMA(bhalf8 a, bhalf8 b, f32x4 c) {
    return __builtin_amdgcn_mfma_f32_16x16x32_bf16(a, b, c, 0, 0, 0);
}
static __device__ inline void gload16(const void* g, void* l) {
    __builtin_amdgcn_global_load_lds(
        (const __attribute__((address_space(1))) unsigned int*)g,
        (__attribute__((address_space(3))) unsigned int*)l, 16, 0, 0);
}
static __device__ inline unsigned int pkbf16(float lo, float hi) {
    union { __hip_bfloat162 h; unsigned int u; } c;
    c.h = __float22bfloat162_rn(make_float2(lo, hi));
    return c.u;
}

// ---------------------------------------------------------------------------
// cast x (fp32 [M][K]) -> bf16 (short) [M][K]
// ---------------------------------------------------------------------------
__global__ __launch_bounds__(256) void cast_x_kernel(const float* __restrict__ x,
                                                     short* __restrict__ o, int n8) {
    int i = blockIdx.x * 256 + threadIdx.x;
    if (i >= n8) return;
    const float4* xv = (const float4*)x;
    float4 a = xv[i * 2];
    float4 b = xv[i * 2 + 1];
    bhalf8 r;
    r[0] = (short)f2bf(a.x); r[1] = (short)f2bf(a.y);
    r[2] = (short)f2bf(a.z); r[3] = (short)f2bf(a.w);
    r[4] = (short)f2bf(b.x); r[5] = (short)f2bf(b.y);
    r[6] = (short)f2bf(b.z); r[7] = (short)f2bf(b.w);
    *(bhalf8*)(o + (size_t)i * 8) = r;
}

// ---------------------------------------------------------------------------
// transpose+cast 4 weight matrices: W fp32 [K][N] -> Wt bf16 [N][K]
// ---------------------------------------------------------------------------
__global__ __launch_bounds__(256) void wtrans_kernel(const float* __restrict__ W0,
                                                     const float* __restrict__ W1,
                                                     const float* __restrict__ W2,
                                                     const float* __restrict__ W3,
                                                     short* __restrict__ out) {
    __shared__ float t[32][33];
    const float* W = (blockIdx.z == 0) ? W0 : (blockIdx.z == 1) ? W1
                     : (blockIdx.z == 2) ? W2 : W3;
    short* o = out + (size_t)blockIdx.z * CDIM * CDIM;
    int n0 = blockIdx.x * 32, k0 = blockIdx.y * 32;
    int tx = threadIdx.x, ty = threadIdx.y;
    for (int j = 0; j < 4; ++j)
        t[ty + j * 8][tx] = W[(size_t)(k0 + ty + j * 8) * CDIM + n0 + tx];
    __syncthreads();
    for (int j = 0; j < 4; ++j)
        o[(size_t)(n0 + ty + j * 8) * CDIM + k0 + tx] = (short)f2bf(t[tx][ty + j * 8]);
}

// ---------------------------------------------------------------------------
// 256x256-tile GEMM, BK=32, K=1024, 512 threads (8 waves, 2x4), dbuf LDS,
// T3-min pipeline. MODE 0: fused QKV (Q scaled by QSCALE); MODE 1: O-proj.
// ---------------------------------------------------------------------------
template <int MODE, int GN>
__global__ __launch_bounds__(512) void gemm256(const short* __restrict__ A,
                                               const short* __restrict__ Bt,
                                               const float* __restrict__ b0,
                                               const float* __restrict__ b1,
                                               const float* __restrict__ b2,
                                               unsigned short* __restrict__ QKout,
                                               unsigned short* __restrict__ Vout,
                                               float* __restrict__ Fout) {
    __shared__ char lds[65536];
    char* AlB0 = lds;
    char* BlB0 = lds + 32768;

    const int tid = threadIdx.x, lane = tid & 63, w = tid >> 6;
    const int g = lane >> 4, t16 = lane & 15;
    const int wr = w >> 2, wc = w & 3;

    const int f = blockIdx.x;
    const int xcd = f & 7, i = f >> 3;
    const int mt = xcd * 4 + i / GN, nt = i % GN;
    const int tm = mt * 256, tn = nt * 256;
    const int part = nt >> 2;

    const int c0 = tid, c1 = 512 + tid;
    const int r0 = c0 >> 2, r1 = c1 >> 2;
    const int k0c = (c0 & 3) ^ ((r0 >> 1) & 3);
    const int k1c = (c1 & 3) ^ ((r1 >> 1) & 3);
    const short* a0 = A + (size_t)(tm + r0) * 1024 + k0c * 8;
    const short* a1 = A + (size_t)(tm + r1) * 1024 + k1c * 8;
    const short* bp0 = Bt + (size_t)(tn + r0) * 1024 + k0c * 8;
    const short* bp1 = Bt + (size_t)(tn + r1) * 1024 + k1c * 8;

    int aoff[8], boff[4];
#pragma unroll
    for (int mi = 0; mi < 8; ++mi) {
        int row = wr * 128 + mi * 16 + t16;
        aoff[mi] = row * 64 + ((g ^ ((row >> 1) & 3)) << 4);
    }
#pragma unroll
    for (int ni = 0; ni < 4; ++ni) {
        int row = wc * 64 + ni * 16 + t16;
        boff[ni] = row * 64 + ((g ^ ((row >> 1) & 3)) << 4);
    }

    f32x4 acc[8][4];
#pragma unroll
    for (int mi = 0; mi < 8; ++mi)
#pragma unroll
        for (int ni = 0; ni < 4; ++ni) acc[mi][ni] = zero4();

#define STAGE(kt_, bb_)                                                   \
    do {                                                                  \
        int off_ = (kt_) * 32;                                            \
        char* al_ = AlB0 + (bb_) * 16384;                                 \
        char* bl_ = BlB0 + (bb_) * 16384;                                 \
        gload16(a0 + off_, al_ + w * 1024);                               \
        gload16(a1 + off_, al_ + 8192 + w * 1024);                        \
        gload16(bp0 + off_, bl_ + w * 1024);                              \
        gload16(bp1 + off_, bl_ + 8192 + w * 1024);                       \
    } while (0)

    STAGE(0, 0);
    __syncthreads();

#pragma unroll 2
    for (int kt = 0; kt < 32; ++kt) {
        const int buf = kt & 1;
        if (kt + 1 < 32) STAGE(kt + 1, buf ^ 1);
        const char* al = AlB0 + buf * 16384;
        const char* bl = BlB0 + buf * 16384;
        bhalf8 af[8], bfr[4];
#pragma unroll
        for (int mi = 0; mi < 8; ++mi) af[mi] = *(const bhalf8*)(al + aoff[mi]);
#pragma unroll
        for (int ni = 0; ni < 4; ++ni) bfr[ni] = *(const bhalf8*)(bl + boff[ni]);
        __builtin_amdgcn_s_setprio(1);
#pragma unroll
        for (int mi = 0; mi < 8; ++mi)
#pragma unroll
            for (int ni = 0; ni < 4; ++ni)
                acc[mi][ni] = MFMA(af[mi], bfr[ni], acc[mi][ni]);
        __builtin_amdgcn_s_setprio(0);
        __syncthreads();
    }
#undef STAGE

    // ------------------ epilogue via LDS (2 m-halves) ------------------
    for (int h = 0; h < 2; ++h) {
        if (h) __syncthreads();
        if (MODE == 0 && part == 2) {
            if (wr == h) {
#pragma unroll
                for (int mi = 0; mi < 8; ++mi)
#pragma unroll
                    for (int ni = 0; ni < 4; ++ni) {
                        int col = wc * 64 + ni * 16 + t16;
                        float bias = b2[(tn + col) & 1023];
#pragma unroll
                        for (int r = 0; r < 4; ++r) {
                            int m_l = mi * 16 + g * 4 + r;
                            int byte = col * 256 + ((m_l * 2) ^ ((col & 7) << 4));
                            *(unsigned short*)(lds + byte) = f2bf(acc[mi][ni][r] + bias);
                        }
                    }
            }
            __syncthreads();
#pragma unroll
            for (int p = 0; p < 8; ++p) {
                int lin = p * 8192 + tid * 16;
                int rv = lin >> 8;
                int inrow = lin & 255;
                int phys = rv * 256 + (inrow ^ ((rv & 7) << 4));
                bhalf8 val = *(const bhalf8*)(lds + phys);
                int m0 = inrow >> 1;
                int n_g = tn + rv;
                int hh = (n_g & 1023) >> 6, d = n_g & 63;
                int m = tm + h * 128 + m0;
                int bi = m >> 11, t0 = m & 2047;
                *(bhalf8*)(Vout + (((size_t)((bi * NHEAD + hh) * HDIM + d)) << 11) + t0) = val;
            }
        } else {
            if (wr == h) {
#pragma unroll
                for (int mi = 0; mi < 8; ++mi)
#pragma unroll
                    for (int ni = 0; ni < 4; ++ni) {
                        int col = wc * 64 + ni * 16 + t16;
                        float bias = 0.f;
                        if (MODE == 0) bias = (part == 0 ? b0 : b1)[(tn + col) & 1023];
#pragma unroll
                        for (int r = 0; r < 4; ++r) {
                            int row_l = mi * 16 + g * 4 + r;
                            float v = acc[mi][ni][r] + bias;
                            if (MODE == 0 && part == 0) v *= QSCALE;
                            int byte = row_l * 512 + ((col * 2) ^ (((row_l >> 2) & 3) << 5));
                            *(unsigned short*)(lds + byte) = f2bf(v);
                        }
                    }
            }
            __syncthreads();
#pragma unroll
            for (int p = 0; p < 8; ++p) {
                int lin = p * 8192 + tid * 16;
                int row_l = lin >> 9;
                int inrow = lin & 511;
                int phys = row_l * 512 + ((inrow & ~31) ^ (((row_l >> 2) & 3) << 5)) + (inrow & 31);
                bhalf8 val = *(const bhalf8*)(lds + phys);
                int col0 = inrow >> 1;
                int n_g = tn + col0;
                int m = tm + h * 128 + row_l;
                if (MODE == 1) {
                    float* op = Fout + (size_t)m * 1024 + n_g;
                    float4 o0, o1;
                    o0.x = bf2f((unsigned short)val[0]) + b0[n_g + 0];
                    o0.y = bf2f((unsigned short)val[1]) + b0[n_g + 1];
                    o0.z = bf2f((unsigned short)val[2]) + b0[n_g + 2];
                    o0.w = bf2f((unsigned short)val[3]) + b0[n_g + 3];
                    o1.x = bf2f((unsigned short)val[4]) + b0[n_g + 4];
                    o1.y = bf2f((unsigned short)val[5]) + b0[n_g + 5];
                    o1.z = bf2f((unsigned short)val[6]) + b0[n_g + 6];
                    o1.w = bf2f((unsigned short)val[7]) + b0[n_g + 7];
                    *(float4*)(op) = o0;
                    *(float4*)(op + 4) = o1;
                } else {
                    int bi = m >> 11, t = m & 2047;
                    int hh = (n_g & 1023) >> 6, d0 = n_g & 63;
                    *(bhalf8*)(QKout +
                               (((size_t)((part * 64 + bi * NHEAD + hh) * SEQ + t)) << 6) + d0) = val;
                }
            }
        }
    }
}

// ---------------------------------------------------------------------------
// Flash attention, causal, double-buffered, swapped QK^T + in-register
// softmax + defer-max. PAIRED q-tiles: block (bh, s) processes q-tile 15-s
// then q-tile s -> every block does exactly 34 kv-tiles (load balance).
// Grid = 64 bh x 8 = 512 blocks, XCD-chunked (8 bh per XCD -> K/V L2-resident).
// ---------------------------------------------------------------------------
__global__ __launch_bounds__(256) void attn_kernel(const short* __restrict__ Q,
                                                   const short* __restrict__ K,
                                                   const short* __restrict__ V,
                                                   unsigned short* __restrict__ ctx) {
    __shared__ short Kl[2][64 * 64];
    __shared__ short Vl[2][64 * 64];
    __shared__ short Pl[4][32 * 64];

    const int tid = threadIdx.x, lane = tid & 63, w = tid >> 6;
    const int g = lane >> 4, t16 = lane & 15;

    // 512 blocks: XCD-chunk swizzle (64 consecutive per XCD = 8 full bh)
    int orig = blockIdx.x;
    int swz = (orig & 7) * 64 + (orig >> 3);
    const int bh = swz >> 3;      // 0..63
    const int sp = swz & 7;       // pair slot 0..7

    const short* Qh = Q + ((size_t)bh << 17);
    const short* Kh = K + ((size_t)bh << 17);
    const short* Vh = V + ((size_t)bh << 17);   // [D][T]

    // hoisted swizzled staging offsets (shorts) + LDS dest offsets (bytes)
    int koff[2], voff[2], ldst[2];
#pragma unroll
    for (int it = 0; it < 2; ++it) {
        int c = it * 256 + tid;
        int srow = c >> 3;
        int dc = (c & 7) ^ (srow & 7);
        koff[it] = (srow << 6) + dc * 8;
        voff[it] = (srow << 11) + dc * 8;
        ldst[it] = it * 4096 + w * 1024;
    }

#define STAGE(kv_, bb_)                                                       \
    do {                                                                      \
        gload16(Kh + koff[0] + ((kv_) << 12), (char*)Kl[bb_] + ldst[0]);      \
        gload16(Kh + koff[1] + ((kv_) << 12), (char*)Kl[bb_] + ldst[1]);      \
        gload16(Vh + voff[0] + ((kv_) << 6), (char*)Vl[bb_] + ldst[0]);       \
        gload16(Vh + voff[1] + ((kv_) << 6), (char*)Vl[bb_] + ldst[1]);       \
    } while (0)

    const int b = bh >> 4, hh = bh & 15;

    STAGE(0, 0);   // phase-0 tile 0

    for (int ph = 0; ph < 2; ++ph) {
        const int qti = (ph == 0) ? (15 - sp) : sp;
        const int qbase = qti * 128;
        const int ntile = 2 * qti + 2;

        // Q B-frags: col=t16 -> q = qbase + w*32 + nf*16 + t16; k = kk*32+g*8+j
        bhalf8 qf[2][2];
#pragma unroll
        for (int nf = 0; nf < 2; ++nf) {
            const short* qp = Qh + ((size_t)(qbase + w * 32 + nf * 16 + t16) << 6) + g * 8;
            qf[nf][0] = *(const bhalf8*)(qp);
            qf[nf][1] = *(const bhalf8*)(qp + 32);
        }

        f32x4 acc[2][4];   // [rf][db]: q = rf*16+g*4+r, d = db*16+t16
#pragma unroll
        for (int rf = 0; rf < 2; ++rf)
#pragma unroll
            for (int i = 0; i < 4; ++i) acc[rf][i] = zero4();
        float m[2], l[2];  // t16-layout
        m[0] = m[1] = -1e30f;
        l[0] = l[1] = 0.f;

        __syncthreads();   // staged tile 0 ready (drains vmcnt)

        int buf = 0;
        for (int kv = 0; kv < ntile; ++kv) {
            if (kv + 1 < ntile) STAGE(kv + 1, buf ^ 1);

            // ---- QK^T (swapped): lg[nf][cb], key=kv*64+cb*16+g*4+r ----
            f32x4 lg[2][4];
            __builtin_amdgcn_s_setprio(1);
#pragma unroll
            for (int cb = 0; cb < 4; ++cb) {
                int s = cb * 16 + t16;
                int sw = (s & 7) << 4;
                const char* rowp = (const char*)Kl[buf] + s * 128;
                bhalf8 k0 = *(const bhalf8*)(rowp + ((g * 16) ^ sw));
                bhalf8 k1 = *(const bhalf8*)(rowp + ((64 + g * 16) ^ sw));
#pragma unroll
                for (int nf = 0; nf < 2; ++nf) {
                    f32x4 z = zero4();
                    z = MFMA(k0, qf[nf][0], z);
                    z = MFMA(k1, qf[nf][1], z);
                    lg[nf][cb] = z;
                }
            }
            __builtin_amdgcn_s_setprio(0);

            // ---- causal mask (diag tiles only) ----
            if (kv >= 2 * qti) {
#pragma unroll
                for (int nf = 0; nf < 2; ++nf) {
                    int row = qbase + w * 32 + nf * 16 + t16;
#pragma unroll
                    for (int cb = 0; cb < 4; ++cb) {
                        int key0 = kv * 64 + cb * 16 + g * 4;
#pragma unroll
                        for (int r = 0; r < 4; ++r)
                            if (key0 + r > row) lg[nf][cb][r] = -1e30f;
                    }
                }
            }

            // ---- in-lane row max + cross-g reduce (2 shfl per nf) ----
            float pm[2];
#pragma unroll
            for (int nf = 0; nf < 2; ++nf) {
                float a = fmaxf(fmaxf(lg[nf][0][0], lg[nf][0][1]),
                                fmaxf(lg[nf][0][2], lg[nf][0][3]));
                float bb = fmaxf(fmaxf(lg[nf][1][0], lg[nf][1][1]),
                                 fmaxf(lg[nf][1][2], lg[nf][1][3]));
                float c = fmaxf(fmaxf(lg[nf][2][0], lg[nf][2][1]),
                                fmaxf(lg[nf][2][2], lg[nf][2][3]));
                float d = fmaxf(fmaxf(lg[nf][3][0], lg[nf][3][1]),
                                fmaxf(lg[nf][3][2], lg[nf][3][3]));
                float t = fmaxf(fmaxf(a, bb), fmaxf(c, d));
                t = fmaxf(t, __shfl_xor(t, 16, 64));
                t = fmaxf(t, __shfl_xor(t, 32, 64));
                pm[nf] = t;
            }

            // ---- defer-max: rescale only when max grew past THR=8 ----
            bool need = (pm[0] > m[0] + 8.f) || (pm[1] > m[1] + 8.f);
            if (__any(need)) {
                float corr[2];
#pragma unroll
                for (int nf = 0; nf < 2; ++nf) {
                    float mn = fmaxf(m[nf], pm[nf]);
                    corr[nf] = exp2f(m[nf] - mn);
                    m[nf] = mn;
                    l[nf] *= corr[nf];
                }
#pragma unroll
                for (int rf = 0; rf < 2; ++rf)
#pragma unroll
                    for (int r = 0; r < 4; ++r) {
                        float c = __shfl(corr[rf], g * 4 + r, 64);
#pragma unroll
                        for (int db = 0; db < 4; ++db) acc[rf][db][r] *= c;
                    }
            }

            // ---- exp2 + partial l + pack + LDS write (8 x ds_write_b64) ----
#pragma unroll
            for (int nf = 0; nf < 2; ++nf) {
                float s_ = 0.f;
                int rowbyte = (nf * 16 + t16) * 128;
                int swb = (t16 & 7) << 4;
#pragma unroll
                for (int cb = 0; cb < 4; ++cb) {
                    float e0 = exp2f(lg[nf][cb][0] - m[nf]);
                    float e1 = exp2f(lg[nf][cb][1] - m[nf]);
                    float e2 = exp2f(lg[nf][cb][2] - m[nf]);
                    float e3 = exp2f(lg[nf][cb][3] - m[nf]);
                    s_ += (e0 + e1) + (e2 + e3);
                    uint2 wv;
                    wv.x = pkbf16(e0, e1);
                    wv.y = pkbf16(e2, e3);
                    int byte = (rowbyte + cb * 32 + g * 8) ^ swb;
                    *(uint2*)((char*)Pl[w] + byte) = wv;
                }
                l[nf] += s_;
            }

            // ---- PV: acc += P @ V ----
            __builtin_amdgcn_s_setprio(1);
#pragma unroll
            for (int kk = 0; kk < 2; ++kk) {
                bhalf8 vf[4];
#pragma unroll
                for (int db = 0; db < 4; ++db) {
                    int d = db * 16 + t16;
                    int vbyte = d * 128 + ((kk * 64 + g * 16) ^ ((d & 7) << 4));
                    vf[db] = *(const bhalf8*)((const char*)Vl[buf] + vbyte);
                }
#pragma unroll
                for (int rf = 0; rf < 2; ++rf) {
                    int lr2 = rf * 16 + t16;
                    int abyte = (lr2 * 128 + kk * 64 + g * 16) ^ ((lr2 & 7) << 4);
                    bhalf8 pa = *(const bhalf8*)((const char*)Pl[w] + abyte);
#pragma unroll
                    for (int db = 0; db < 4; ++db)
                        acc[rf][db] = MFMA(pa, vf[db], acc[rf][db]);
                }
            }
            __builtin_amdgcn_s_setprio(0);

            __syncthreads();
            buf ^= 1;
        }

        // prefetch phase-1 tile 0 (hides under epilogue; ntile is even so
        // buf==0 here and Kl[0]/Vl[0] reads completed 2 barriers ago)
        if (ph == 0) STAGE(0, 0);

        // ---- finalize l (2 shfl), broadcast 1/l, write ctx ----
        float linv[2];
#pragma unroll
        for (int nf = 0; nf < 2; ++nf) {
            float t = l[nf];
            t += __shfl_xor(t, 16, 64);
            t += __shfl_xor(t, 32, 64);
            linv[nf] = 1.f / t;
        }
#pragma unroll
        for (int rf = 0; rf < 2; ++rf)
#pragma unroll
            for (int r = 0; r < 4; ++r) {
                float inv = __shfl(linv[rf], g * 4 + r, 64);
                int t = qbase + w * 32 + rf * 16 + g * 4 + r;
                size_t rowoff = (((size_t)(b * SEQ + t)) << 10) + hh * 64;
#pragma unroll
                for (int db = 0; db < 4; ++db)
                    ctx[rowoff + db * 16 + t16] = f2bf(acc[rf][db][r] * inv);
            }
    }
#undef STAGE
}

// ---------------------------------------------------------------------------
// launch
// ---------------------------------------------------------------------------
extern "C" void kernel_launch(void* const* d_in, const int* in_sizes, int n_in,
                              void* d_out, int out_size, void* d_ws, size_t ws_size,
                              hipStream_t stream) {
    const float* x  = (const float*)d_in[0];
    const float* Wq = (const float*)d_in[1];
    const float* bq = (const float*)d_in[2];
    const float* Wk = (const float*)d_in[3];
    const float* bk = (const float*)d_in[4];
    const float* Wv = (const float*)d_in[5];
    const float* bv = (const float*)d_in[6];
    const float* Wo = (const float*)d_in[7];
    const float* bo = (const float*)d_in[8];

    char* ws = (char*)d_ws;
    short* x16 = (short*)(ws);                                // 16 MB
    short* Wt  = (short*)(ws + (size_t)16 * 1024 * 1024);     // q,k,v,o 2MB each
    short* Wot = Wt + (size_t)3 * CDIM * CDIM;
    short* Qb  = (short*)(ws + (size_t)24 * 1024 * 1024);     // 32 MB Q||K
    short* Vb  = (short*)(ws + (size_t)56 * 1024 * 1024);     // 16 MB [BH][D][T]
    short* Ctx = (short*)(ws + (size_t)72 * 1024 * 1024);     // 16 MB [M][C]

    cast_x_kernel<<<dim3(MTOT * CDIM / 8 / 256), dim3(256), 0, stream>>>(
        x, x16, MTOT * CDIM / 8);
    wtrans_kernel<<<dim3(32, 32, 4), dim3(32, 8), 0, stream>>>(Wq, Wk, Wv, Wo, Wt);

    // fused QKV projection: N = 3072 (Wq||Wk||Wv rows), 384 blocks
    gemm256<0, 12><<<dim3(384), dim3(512), 0, stream>>>(
        x16, Wt, bq, bk, bv, (unsigned short*)Qb, (unsigned short*)Vb, nullptr);

    // attention: 512 paired blocks (K part = Qb + 64*SEQ*HDIM)
    attn_kernel<<<dim3(512), dim3(256), 0, stream>>>(
        Qb, Qb + (size_t)64 * SEQ * HDIM, Vb, (unsigned short*)Ctx);

    // output projection -> fp32 d_out, 128 blocks
    gemm256<1, 4><<<dim3(128), dim3(512), 0, stream>>>(
        Ctx, Wot, bo, nullptr, nullptr, nullptr, nullptr, (float*)d_out);
}